// Round 7
// baseline (777.228 us; speedup 1.0000x reference)
//
#include <hip/hip_runtime.h>
#include <math.h>

#define NNODES 20000
#define NPAD   20096   // 157 * 128
#define NEDGES 160000
#define HIDDIM 128
#define NHEADS 8
#define NGRAPH 64
#define KC 384   // concatenated K (hi | lo | hi)
#define GXTILES 157

typedef short short8 __attribute__((ext_vector_type(8)));
typedef float floatx4 __attribute__((ext_vector_type(4)));
typedef unsigned short ushort4v __attribute__((ext_vector_type(4)));

__device__ inline unsigned short f2bf(float x) {
    unsigned u = __float_as_uint(x);
    u += 0x7fff + ((u >> 16) & 1);
    return (unsigned short)(u >> 16);
}
__device__ inline float bf2f(unsigned short h) {
    return __uint_as_float(((unsigned)h) << 16);
}

// async global->LDS DMA, 16B per lane (HW: lds dst = uniform base + lane*16)
__device__ __forceinline__ void gload16(const unsigned short* g, unsigned short* l) {
    __builtin_amdgcn_global_load_lds(
        (const __attribute__((address_space(1))) unsigned int*)g,
        (__attribute__((address_space(3))) unsigned int*)l, 16, 0, 0);
}

// ---------------- utility ----------------
__global__ __launch_bounds__(256) void zero_kernel(float* __restrict__ p, int n) {
    int i = blockIdx.x * blockDim.x + threadIdx.x;
    if (i < n) p[i] = 0.f;
}

// ---------------- CSR build ----------------
__global__ __launch_bounds__(256) void count_deg_kernel(const int* __restrict__ dst,
                                                        int* __restrict__ deg, int e) {
    int i = blockIdx.x * blockDim.x + threadIdx.x;
    if (i < e) atomicAdd(&deg[dst[i]], 1);
}

__global__ __launch_bounds__(256) void scan1_kernel(const int* __restrict__ deg,
                                                    int* __restrict__ chunk,
                                                    int* __restrict__ bsum, int n) {
    __shared__ int buf[256];
    int t = threadIdx.x;
    int i = blockIdx.x * 256 + t;
    int v = (i < n) ? deg[i] : 0;
    buf[t] = v;
    __syncthreads();
    for (int off = 1; off < 256; off <<= 1) {
        int tmp = (t >= off) ? buf[t - off] : 0;
        __syncthreads();
        buf[t] += tmp;
        __syncthreads();
    }
    if (i < n) chunk[i] = buf[t];
    if (t == 255) bsum[blockIdx.x] = buf[255];
}

__global__ __launch_bounds__(128) void scan2_kernel(int* __restrict__ bsum, int nb) {
    __shared__ int buf[128];
    int t = threadIdx.x;
    int v = (t < nb) ? bsum[t] : 0;
    buf[t] = v;
    __syncthreads();
    for (int off = 1; off < 128; off <<= 1) {
        int tmp = (t >= off) ? buf[t - off] : 0;
        __syncthreads();
        buf[t] += tmp;
        __syncthreads();
    }
    if (t < nb) bsum[t] = buf[t] - v;
}

__global__ __launch_bounds__(256) void scan3_kernel(const int* __restrict__ chunk,
                                                    const int* __restrict__ bsum,
                                                    int* __restrict__ offs, int n) {
    int i = blockIdx.x * 256 + threadIdx.x;
    if (i < n) offs[i + 1] = chunk[i] + bsum[i >> 8];
    if (i == 0) offs[0] = 0;
}

// scatter (edges) + graph-boundary detection (nodes) fused: one dispatch
__global__ __launch_bounds__(256) void scatter_gb_kernel(
    const int* __restrict__ src, const int* __restrict__ dst,
    const int* __restrict__ offs, int* __restrict__ cursor,
    int* __restrict__ csr_src, int e,
    const int* __restrict__ batch, int* __restrict__ gs, int* __restrict__ ge, int n) {
    int i = blockIdx.x * blockDim.x + threadIdx.x;
    if (i < e) {
        int d = dst[i];
        int pos = offs[d] + atomicAdd(&cursor[d], 1);
        csr_src[pos] = src[i];
    }
    if (i < n) {
        int b = batch[i];
        if (i == 0 || batch[i - 1] != b) gs[b] = i;
        if (i == n - 1 || batch[i + 1] != b) ge[b] = i + 1;
    }
}

// ---------------- ALL weight prep in one dispatch ----------------
// Blocks [0,1536): layers 0-2 q|k|v|s rows; [1536,1664): Wp rows;
// [1664,2688): skip (t rows, filled below); [2688,2816): Ws3 rows;
// [2816,2837): bias entries; [2837,3861): mqk t rows; [3861,3989): Wvm rows.
__global__ __launch_bounds__(128) void prep_all_kernel(
    const float* __restrict__ Wq, const float* __restrict__ Wk,
    const float* __restrict__ Wv, const float* __restrict__ Ws,
    const float* __restrict__ Wp, const float* __restrict__ Ws3,
    const float* __restrict__ bq, const float* __restrict__ bk,
    const float* __restrict__ bv, const float* __restrict__ bs,
    const float* __restrict__ bs3,
    const float* __restrict__ Wq3, const float* __restrict__ Wk3,
    const float* __restrict__ bq3,
    const float* __restrict__ Wv3, const float* __restrict__ bv3,
    unsigned short* __restrict__ WtAll, float* __restrict__ bcat,
    unsigned short* __restrict__ Wvm, float* __restrict__ bvm) {
    int id = blockIdx.x;
    int k = threadIdx.x;
    if (id >= 3861) {  // Wvm rows
        int j = id - 3861;
#pragma unroll
        for (int h = 0; h < 8; ++h) {
            float w = Wv3[(size_t)k * 1024 + h * 128 + j] * 0.125f;
            Wvm[(size_t)j * 1024 + h * 128 + k] = f2bf(w);
        }
        if (k == 0) {
            float s = 0.f;
            for (int h = 0; h < 8; ++h) s += bv3[h * 128 + j];
            bvm[j] = s * 0.125f;
        }
        return;
    }
    if (id >= 2837) {  // mqk t rows: M_h = Wq_h Wk_h^T
        int hb = id - 2837;
        int h = hb >> 7, b = hb & 127;
        __shared__ float wk[128];
        wk[k] = Wk3[(size_t)b * 1024 + h * 128 + k];
        __syncthreads();
        const float* wq = Wq3 + (size_t)k * 1024 + h * 128;
        float acc = 0.f;
#pragma unroll 16
        for (int d = 0; d < 128; ++d) acc = fmaf(wq[d], wk[d], acc);
        unsigned short hi = f2bf(acc);
        unsigned short lo = f2bf(acc - bf2f(hi));
        unsigned short* dst = WtAll + (size_t)(1664 + h * 128 + b) * KC;
        dst[k] = hi;
        dst[128 + k] = hi;
        dst[256 + k] = lo;
        if (k == 0) {
            float bb = 0.f;
            for (int d = 0; d < 128; ++d) bb = fmaf(bq3[h * 128 + d], wk[d], bb);
            bcat[1536 + h * 128 + b] = bb;
        }
        return;
    }
    if (id >= 2816) {  // bias
        int idx = (id - 2816) * 128 + k;
        if (idx >= 2688) return;
        float v;
        if (idx < 1536) {
            int li = idx / 512, n = idx % 512, sel = n >> 7, np = n & 127;
            const float* b = (sel == 0) ? bq : (sel == 1) ? bk : (sel == 2) ? bv : bs;
            v = b[li * 128 + np];
        } else if (idx < 2560) {
            return;  // t bias filled above
        } else {
            v = bs3[idx - 2560];
        }
        bcat[idx] = v;
        return;
    }
    float w;
    if (id < 1536) {
        int li = id / 512, n = id % 512, sel = n >> 7, np = n & 127;
        const float* W = (sel == 0) ? Wq : (sel == 1) ? Wk : (sel == 2) ? Wv : Ws;
        w = W[li * 16384 + k * 128 + np];
    } else if (id < 1664) {
        w = Wp[k * 128 + (id - 1536)];
    } else if (id < 2688) {
        return;  // t rows handled by mqk branch
    } else {
        w = Ws3[k * 128 + (id - 2688)];
    }
    unsigned short hi = f2bf(w);
    unsigned short lo = f2bf(w - bf2f(hi));
    unsigned short* dst = WtAll + (size_t)id * KC;
    dst[k] = hi;
    dst[128 + k] = hi;
    dst[256 + k] = lo;
}

// ---------------- activation -> split-bf16 A_cat ----------------
__global__ __launch_bounds__(256) void cat_from_kernel(const float* __restrict__ h,
                                                       unsigned short* __restrict__ Acat) {
    int idx = blockIdx.x * 256 + threadIdx.x;
    if (idx >= NPAD * HIDDIM) return;
    int r = idx >> 7, k = idx & 127;
    float x = (r < NNODES) ? h[idx] : 0.f;
    unsigned short hi = f2bf(x);
    unsigned short lo = f2bf(x - bf2f(hi));
    unsigned short* row = Acat + (size_t)r * KC;
    row[k] = hi;
    row[128 + k] = lo;
    row[256 + k] = hi;
}

// ---------------- LDS-staged MFMA GEMM (XCD swizzle, global_load_lds) ----------------
// Tile: 128 nodes x 128 feats per block, 4 waves. BK=32 double-buffered LDS
// (32KB), staging via global_load_lds width 16. Chunk-XOR swizzle on BOTH
// the pre-swizzled global source and the ds_read address (rule 21).
// OMODE: 0 = f32 out (stride M), 1 = bf16 out (stride M),
//        2 = Acat hi|lo|hi out (stride KC; safe in-place for BY=1).
template <typename OutT, int KG, int BY, int ST, int OMODE>
__global__ __launch_bounds__(256) void gemm_lds_kernel(
    const unsigned short* __restrict__ A, const unsigned short* __restrict__ Wt,
    const float* __restrict__ bias, OutT* __restrict__ C, int M, int nrows) {
    int id = blockIdx.x;
    int xcd = id & 7;
    int idx = id >> 3;
    int bx = (idx / BY) * 8 + xcd;
    int by = idx % BY;
    if (bx >= GXTILES) return;

    __shared__ unsigned short lds[2][2][4096];  // [buf][A/W][128 rows * 32 shorts]

    int tid = threadIdx.x;
    int lane = tid & 63;
    int wave = tid >> 6;
    int m = lane & 15;
    int q = lane >> 4;
    int nodeBase = bx * 128 + (wave & 1) * 64;
    int featBase = by * 128 + (wave >> 1) * 64;

    const unsigned short* gA = A + (size_t)bx * 128 * ST;
    const unsigned short* gW = Wt + (size_t)by * 128 * ST;

    int rs = lane >> 2;
    int cp0 = lane & 3;

    auto stagef = [&](int buf, int kk) {
        int kof = kk * 32;
#pragma unroll
        for (int jj = 0; jj < 2; ++jj) {
            int j = wave * 2 + jj;
            int row = j * 16 + rs;
            int g = cp0 ^ ((row >> 1) & 3);
            gload16(gA + (size_t)row * ST + kof + g * 8,
                    &lds[buf][0][0] + (size_t)j * 512);
            gload16(gW + (size_t)row * ST + kof + g * 8,
                    &lds[buf][1][0] + (size_t)j * 512);
        }
    };

    floatx4 acc[4][4];
#pragma unroll
    for (int r = 0; r < 4; ++r)
#pragma unroll
        for (int c = 0; c < 4; ++c) acc[r][c] = (floatx4){0.f, 0.f, 0.f, 0.f};

    stagef(0, 0);
    __syncthreads();

    for (int kg = 0; kg < KG; ++kg) {
        int cur = kg & 1;
        if (kg + 1 < KG) stagef(cur ^ 1, kg + 1);
        short8 a[4], b[4];
#pragma unroll
        for (int r = 0; r < 4; ++r) {
            int wr = (wave >> 1) * 64 + r * 16 + m;
            int cp = q ^ ((wr >> 1) & 3);
            a[r] = *(const short8*)(&lds[cur][1][0] + wr * 32 + cp * 8);
        }
#pragma unroll
        for (int c = 0; c < 4; ++c) {
            int ar = (wave & 1) * 64 + c * 16 + m;
            int cp = q ^ ((ar >> 1) & 3);
            b[c] = *(const short8*)(&lds[cur][0][0] + ar * 32 + cp * 8);
        }
#pragma unroll
        for (int r = 0; r < 4; ++r)
#pragma unroll
            for (int c = 0; c < 4; ++c)
                acc[r][c] = __builtin_amdgcn_mfma_f32_16x16x32_bf16(a[r], b[c], acc[r][c], 0, 0, 0);
        __syncthreads();
    }

    float4 bv[4];
#pragma unroll
    for (int r = 0; r < 4; ++r) bv[r] = *(const float4*)(bias + featBase + r * 16 + q * 4);
#pragma unroll
    for (int c = 0; c < 4; ++c) {
        int node = nodeBase + c * 16 + m;
        if (node < nrows) {
#pragma unroll
            for (int r = 0; r < 4; ++r) {
                int f0 = featBase + r * 16 + q * 4;
                float v0 = acc[r][c][0] + bv[r].x;
                float v1 = acc[r][c][1] + bv[r].y;
                float v2 = acc[r][c][2] + bv[r].z;
                float v3 = acc[r][c][3] + bv[r].w;
                if (OMODE == 2) {
                    unsigned short* row = (unsigned short*)C + (size_t)node * KC;
                    unsigned short h0 = f2bf(v0), h1 = f2bf(v1), h2 = f2bf(v2), h3 = f2bf(v3);
                    ushort4v hiv = {h0, h1, h2, h3};
                    ushort4v lov = {f2bf(v0 - bf2f(h0)), f2bf(v1 - bf2f(h1)),
                                    f2bf(v2 - bf2f(h2)), f2bf(v3 - bf2f(h3))};
                    *(ushort4v*)(row + f0) = hiv;
                    *(ushort4v*)(row + 128 + f0) = lov;
                    *(ushort4v*)(row + 256 + f0) = hiv;
                } else if (OMODE == 1) {
                    ushort4v o = {f2bf(v0), f2bf(v1), f2bf(v2), f2bf(v3)};
                    *(ushort4v*)((unsigned short*)C + (size_t)node * M + f0) = o;
                } else {
                    float4 o = {v0, v1, v2, v3};
                    *(float4*)((float*)C + (size_t)node * M + f0) = o;
                }
            }
        }
    }
}

// ---------------- attention layers 0-2: 4 nodes/block + fused BN stats ----------------
// Each node owns one 64-lane wave (shfl stays intra-wave). Block-level
// partial BN stats in LDS, one global atomicAdd per feature per block
// (5000 adds/address, L2-pipelined — same scale as count_deg's atomics).
__global__ __launch_bounds__(256) void attn_small_kernel(
    const unsigned short* __restrict__ qkvs,
    const float* __restrict__ Wb,
    const int* __restrict__ offs, const int* __restrict__ csr_src,
    float* __restrict__ out, float* __restrict__ stat) {
    int tid = threadIdx.x;
    int i = blockIdx.x * 4 + (tid >> 6);
    int l = tid & 63;
    __shared__ float ssum[128], ssq[128];
    if (tid < 128) { ssum[tid] = 0.f; ssq[tid] = 0.f; }
    __syncthreads();
    int g = l >> 5;
    int d0 = (l & 31) * 4;
    uint2 qraw = *(const uint2*)(qkvs + (size_t)i * 512 + d0);
    uint2 rraw = *(const uint2*)(qkvs + (size_t)i * 512 + 384 + d0);
    float q0 = bf2f((unsigned short)(qraw.x & 0xffff)), q1 = bf2f((unsigned short)(qraw.x >> 16));
    float q2 = bf2f((unsigned short)(qraw.y & 0xffff)), q3 = bf2f((unsigned short)(qraw.y >> 16));
    int e0 = offs[i], e1 = offs[i + 1];
    float lac = 0.f;
    float a0 = 0.f, a1 = 0.f, a2 = 0.f, a3 = 0.f;
    int e = e0 + g;
    uint2 kk_n = {0, 0}, vv_n = {0, 0};
    if (e < e1) {
        int sn = csr_src[e];
        const unsigned short* row = qkvs + (size_t)sn * 512;
        kk_n = *(const uint2*)(row + 128 + d0);
        vv_n = *(const uint2*)(row + 256 + d0);
    }
    while (e < e1) {
        uint2 kk = kk_n, vv = vv_n;
        int en = e + 2;
        if (en < e1) {
            int sn2 = csr_src[en];
            const unsigned short* row2 = qkvs + (size_t)sn2 * 512;
            kk_n = *(const uint2*)(row2 + 128 + d0);
            vv_n = *(const uint2*)(row2 + 256 + d0);
        }
        float k0 = bf2f((unsigned short)(kk.x & 0xffff)), k1 = bf2f((unsigned short)(kk.x >> 16));
        float k2 = bf2f((unsigned short)(kk.y & 0xffff)), k3 = bf2f((unsigned short)(kk.y >> 16));
        float p = q0 * k0 + q1 * k1 + q2 * k2 + q3 * k3;
        p += __shfl_xor(p, 1);
        p += __shfl_xor(p, 2);
        float w = __expf(p * 0.25f);
        float v0 = bf2f((unsigned short)(vv.x & 0xffff)), v1 = bf2f((unsigned short)(vv.x >> 16));
        float v2 = bf2f((unsigned short)(vv.y & 0xffff)), v3 = bf2f((unsigned short)(vv.y >> 16));
        a0 += w * v0;
        a1 += w * v1;
        a2 += w * v2;
        a3 += w * v3;
        lac += w;
        e = en;
    }
    a0 += __shfl_xor(a0, 32);
    a1 += __shfl_xor(a1, 32);
    a2 += __shfl_xor(a2, 32);
    a3 += __shfl_xor(a3, 32);
    lac += __shfl_xor(lac, 32);
    float inv = 1.f / (lac + 1e-16f);
    float o0 = a0 * inv, o1 = a1 * inv, o2 = a2 * inv, o3 = a3 * inv;
    float r0 = bf2f((unsigned short)(rraw.x & 0xffff)), r1 = bf2f((unsigned short)(rraw.x >> 16));
    float r2 = bf2f((unsigned short)(rraw.y & 0xffff)), r3 = bf2f((unsigned short)(rraw.y >> 16));
    float part = o0 * Wb[d0] + o1 * Wb[d0 + 1] + o2 * Wb[d0 + 2] + o3 * Wb[d0 + 3]
               + r0 * Wb[128 + d0] + r1 * Wb[128 + d0 + 1]
               + r2 * Wb[128 + d0 + 2] + r3 * Wb[128 + d0 + 3]
               + (o0 - r0) * Wb[256 + d0] + (o1 - r1) * Wb[256 + d0 + 1]
               + (o2 - r2) * Wb[256 + d0 + 2] + (o3 - r3) * Wb[256 + d0 + 3];
    if (g) part = 0.f;
#pragma unroll
    for (int msk = 1; msk <= 32; msk <<= 1) part += __shfl_xor(part, msk);
    float gg = 1.f / (1.f + __expf(-part));
    if (g == 0) {
        float w0 = gg * r0 + (1.f - gg) * o0;
        float w1 = gg * r1 + (1.f - gg) * o1;
        float w2 = gg * r2 + (1.f - gg) * o2;
        float w3 = gg * r3 + (1.f - gg) * o3;
        float4 o4 = {w0, w1, w2, w3};
        *(float4*)(out + (size_t)i * HIDDIM + d0) = o4;
        atomicAdd(&ssum[d0], w0);     atomicAdd(&ssq[d0], w0 * w0);
        atomicAdd(&ssum[d0 + 1], w1); atomicAdd(&ssq[d0 + 1], w1 * w1);
        atomicAdd(&ssum[d0 + 2], w2); atomicAdd(&ssq[d0 + 2], w2 * w2);
        atomicAdd(&ssum[d0 + 3], w3); atomicAdd(&ssq[d0 + 3], w3 * w3);
    }
    __syncthreads();
    if (tid < 128) {
        atomicAdd(&stat[tid], ssum[tid]);
        atomicAdd(&stat[HIDDIM + tid], ssq[tid]);
    }
}

// ---------------- attention layer 3: 4 nodes/block, pipelined edge loop --------
// t node-major [N][1152] (t at 0, s at 1024). agg node-major [N][1024] bf16.
__global__ __launch_bounds__(256) void attn_big_kernel(
    const unsigned short* __restrict__ tbuf, const unsigned short* __restrict__ Acat,
    const int* __restrict__ offs, const int* __restrict__ csr_src,
    unsigned short* __restrict__ agg) {
    int tid = threadIdx.x;
    int i = blockIdx.x * 4 + (tid >> 6);
    int l = tid & 63;
    int doff = (l & 7) * 16;
    const unsigned short* tp = tbuf + (size_t)i * 1152 + l * 16;
    uint4 t0 = *(const uint4*)tp;
    uint4 t1 = *(const uint4*)(tp + 8);
    float tq[16];
    tq[0] = bf2f((unsigned short)(t0.x & 0xffff)); tq[1] = bf2f((unsigned short)(t0.x >> 16));
    tq[2] = bf2f((unsigned short)(t0.y & 0xffff)); tq[3] = bf2f((unsigned short)(t0.y >> 16));
    tq[4] = bf2f((unsigned short)(t0.z & 0xffff)); tq[5] = bf2f((unsigned short)(t0.z >> 16));
    tq[6] = bf2f((unsigned short)(t0.w & 0xffff)); tq[7] = bf2f((unsigned short)(t0.w >> 16));
    tq[8] = bf2f((unsigned short)(t1.x & 0xffff)); tq[9] = bf2f((unsigned short)(t1.x >> 16));
    tq[10] = bf2f((unsigned short)(t1.y & 0xffff)); tq[11] = bf2f((unsigned short)(t1.y >> 16));
    tq[12] = bf2f((unsigned short)(t1.z & 0xffff)); tq[13] = bf2f((unsigned short)(t1.z >> 16));
    tq[14] = bf2f((unsigned short)(t1.w & 0xffff)); tq[15] = bf2f((unsigned short)(t1.w >> 16));
    int e0 = offs[i], e1 = offs[i + 1];
    float ac[16];
#pragma unroll
    for (int j = 0; j < 16; ++j) ac[j] = 0.f;
    float lac = 0.f;
    int e = e0;
    uint4 k0n = {0, 0, 0, 0}, k1n = {0, 0, 0, 0};
    if (e < e1) {
        const unsigned short* hp = Acat + (size_t)csr_src[e] * KC + doff;
        k0n = *(const uint4*)hp;
        k1n = *(const uint4*)(hp + 8);
    }
    while (e < e1) {
        uint4 k0 = k0n, k1 = k1n;
        int en = e + 1;
        if (en < e1) {
            const unsigned short* hp2 = Acat + (size_t)csr_src[en] * KC + doff;
            k0n = *(const uint4*)hp2;
            k1n = *(const uint4*)(hp2 + 8);
        }
        float kk[16];
        kk[0] = bf2f((unsigned short)(k0.x & 0xffff)); kk[1] = bf2f((unsigned short)(k0.x >> 16));
        kk[2] = bf2f((unsigned short)(k0.y & 0xffff)); kk[3] = bf2f((unsigned short)(k0.y >> 16));
        kk[4] = bf2f((unsigned short)(k0.z & 0xffff)); kk[5] = bf2f((unsigned short)(k0.z >> 16));
        kk[6] = bf2f((unsigned short)(k0.w & 0xffff)); kk[7] = bf2f((unsigned short)(k0.w >> 16));
        kk[8] = bf2f((unsigned short)(k1.x & 0xffff)); kk[9] = bf2f((unsigned short)(k1.x >> 16));
        kk[10] = bf2f((unsigned short)(k1.y & 0xffff)); kk[11] = bf2f((unsigned short)(k1.y >> 16));
        kk[12] = bf2f((unsigned short)(k1.z & 0xffff)); kk[13] = bf2f((unsigned short)(k1.z >> 16));
        kk[14] = bf2f((unsigned short)(k1.w & 0xffff)); kk[15] = bf2f((unsigned short)(k1.w >> 16));
        float p = 0.f;
#pragma unroll
        for (int j = 0; j < 16; ++j) p = fmaf(tq[j], kk[j], p);
        p += __shfl_xor(p, 1);
        p += __shfl_xor(p, 2);
        p += __shfl_xor(p, 4);
        float w = __expf(p * 0.08838834764831845f);
#pragma unroll
        for (int j = 0; j < 16; ++j) ac[j] = fmaf(w, kk[j], ac[j]);
        lac += w;
        e = en;
    }
    float inv = 1.f / (lac + 1e-16f);
    unsigned short* o = agg + (size_t)i * 1024 + l * 16;
    ushort4v o0 = {f2bf(ac[0] * inv), f2bf(ac[1] * inv), f2bf(ac[2] * inv), f2bf(ac[3] * inv)};
    ushort4v o1 = {f2bf(ac[4] * inv), f2bf(ac[5] * inv), f2bf(ac[6] * inv), f2bf(ac[7] * inv)};
    ushort4v o2 = {f2bf(ac[8] * inv), f2bf(ac[9] * inv), f2bf(ac[10] * inv), f2bf(ac[11] * inv)};
    ushort4v o3 = {f2bf(ac[12] * inv), f2bf(ac[13] * inv), f2bf(ac[14] * inv), f2bf(ac[15] * inv)};
    *(ushort4v*)o = o0;
    *(ushort4v*)(o + 4) = o1;
    *(ushort4v*)(o + 8) = o2;
    *(ushort4v*)(o + 12) = o3;
}

// ---------------- beta gate layer 3 + BN stats, fused (grid-stride) ----------------
// Also zeroes the 64x128 pool output (blocks 0..63).
__global__ __launch_bounds__(128) void beta3_stats_kernel(
    const float* __restrict__ omean, const unsigned short* __restrict__ tbuf,
    const float* __restrict__ Wb, float* __restrict__ out,
    float* __restrict__ stat, int n, float* __restrict__ pool_out) {
    int t = threadIdx.x;
    if (blockIdx.x < NGRAPH) pool_out[blockIdx.x * HIDDIM + t] = 0.f;
    __shared__ float wsum[2];
    float s = 0.f, sq = 0.f;
    for (int i = blockIdx.x; i < n; i += gridDim.x) {
        float o = omean[(size_t)i * HIDDIM + t];
        float r = bf2f(tbuf[(size_t)i * 1152 + 1024 + t]);
        float part = o * Wb[t] + r * Wb[128 + t] + (o - r) * Wb[256 + t];
#pragma unroll
        for (int msk = 1; msk <= 32; msk <<= 1) part += __shfl_xor(part, msk);
        if ((t & 63) == 0) wsum[t >> 6] = part;
        __syncthreads();
        float tot = wsum[0] + wsum[1];
        __syncthreads();
        float g = 1.f / (1.f + __expf(-tot));
        float v = g * r + (1.f - g) * o;
        out[(size_t)i * HIDDIM + t] = v;
        s += v;
        sq += v * v;
    }
    atomicAdd(&stat[t], s);
    atomicAdd(&stat[HIDDIM + t], sq);
}

// ---------------- batchnorm apply (layers 0-2) ----------------
__global__ __launch_bounds__(128) void bn_apply_kernel(float* __restrict__ x,
                                                       const float* __restrict__ stat,
                                                       const float* __restrict__ gamma,
                                                       const float* __restrict__ beta, int n,
                                                       unsigned short* __restrict__ cat) {
    int t = threadIdx.x;
    float mu = stat[t] / (float)n;
    float var = stat[HIDDIM + t] / (float)n - mu * mu;
    float rs = rsqrtf(var + 1e-5f);
    float g = gamma[t], b = beta[t];
    for (int i = blockIdx.x; i < n; i += gridDim.x) {
        float v = x[(size_t)i * HIDDIM + t];
        v = fmaxf((v - mu) * rs * g + b, 0.f);
        x[(size_t)i * HIDDIM + t] = v;
        if (cat) {
            unsigned short hi = f2bf(v);
            unsigned short lo = f2bf(v - bf2f(hi));
            unsigned short* row = cat + (size_t)i * KC;
            row[t] = hi;
            row[128 + t] = lo;
            row[256 + t] = hi;
        }
    }
}

// ---------------- pool: fused BN+ReLU+mean, 16-way parallel partials ----------------
__global__ __launch_bounds__(256) void pool_bn_part_kernel(
    const float* __restrict__ x, const float* __restrict__ stat,
    const float* __restrict__ gamma, const float* __restrict__ beta,
    const int* __restrict__ gs, const int* __restrict__ ge,
    float* __restrict__ out, int n) {
    int g = blockIdx.x, c = blockIdx.y;
    int t = threadIdx.x;
    int f = t & 127, half = t >> 7;
    float mu = stat[f] / (float)n;
    float var = stat[HIDDIM + f] / (float)n - mu * mu;
    float rs = rsqrtf(var + 1e-5f);
    float ga = gamma[f], be = beta[f];
    int s = gs[g], e = ge[g];
    float acc = 0.f;
    for (int i = s + 2 * c + half; i < e; i += 16)
        acc += fmaxf((x[(size_t)i * HIDDIM + f] - mu) * rs * ga + be, 0.f);
    __shared__ float l0[128];
    if (half == 0) l0[f] = acc;
    __syncthreads();
    if (half == 1) {
        int cnt = e - s;
        float inv = 1.f / (float)(cnt > 0 ? cnt : 1);
        atomicAdd(&out[g * HIDDIM + f], (l0[f] + acc) * inv);
    }
}

// ---------------- host ----------------
extern "C" void kernel_launch(void* const* d_in, const int* in_sizes, int n_in,
                              void* d_out, int out_size, void* d_ws, size_t ws_size,
                              hipStream_t stream) {
    const float* x       = (const float*)d_in[0];
    const int*   ei      = (const int*)d_in[1];
    const int*   batch   = (const int*)d_in[2];
    const float* Wp      = (const float*)d_in[3];
    const float* bp      = (const float*)d_in[4];
    const float* Wq      = (const float*)d_in[5];
    const float* bq      = (const float*)d_in[6];
    const float* Wk      = (const float*)d_in[7];
    const float* bk      = (const float*)d_in[8];
    const float* Wv      = (const float*)d_in[9];
    const float* bv      = (const float*)d_in[10];
    const float* Ws      = (const float*)d_in[11];
    const float* bs      = (const float*)d_in[12];
    const float* Wbeta   = (const float*)d_in[13];
    const float* Wq3     = (const float*)d_in[14];
    const float* bq3     = (const float*)d_in[15];
    const float* Wk3     = (const float*)d_in[16];
    const float* bk3     = (const float*)d_in[17];
    const float* Wv3     = (const float*)d_in[18];
    const float* bv3     = (const float*)d_in[19];
    const float* Ws3     = (const float*)d_in[20];
    const float* bs3     = (const float*)d_in[21];
    const float* Wbeta3  = (const float*)d_in[22];
    const float* bn_gamma = (const float*)d_in[23];
    const float* bn_beta  = (const float*)d_in[24];
    float* out = (float*)d_out;
    (void)bk3;

    const int* esrc = ei;
    const int* edst = ei + NEDGES;

    char* wpc = (char*)d_ws;
    auto alloc = [&](size_t nbytes) -> char* {
        char* p = wpc;
        wpc += (nbytes + 255) & ~(size_t)255;
        return p;
    };
    unsigned short* Acat  = (unsigned short*)alloc((size_t)NPAD * KC * 2);      // 15.4 MB
    unsigned short* WtAll = (unsigned short*)alloc((size_t)2816 * KC * 2);      // 2.2 MB
    float* bcat   = (float*)alloc(2688 * 4);
    unsigned short* Wvm   = (unsigned short*)alloc((size_t)128 * 1024 * 2);     // 256 KB
    float* bvm    = (float*)alloc(128 * 4);
    unsigned short* tbuf  = (unsigned short*)alloc((size_t)NPAD * 1152 * 2);    // 46.3 MB (alias qkvs)
    unsigned short* aggb  = (unsigned short*)alloc((size_t)NPAD * 1024 * 2);    // 41 MB
    float* omean  = (float*)alloc((size_t)NNODES * HIDDIM * 4);                 // 10.2 MB
    float* hbuf   = (float*)alloc((size_t)NNODES * HIDDIM * 4);
    float* obuf   = (float*)alloc((size_t)NNODES * HIDDIM * 4);
    int*   deg    = (int*)alloc((2 * NNODES + 128 + 4 * 256) * 4);
    int*   cursor = deg + NNODES;
    int*   gs     = deg + 2 * NNODES;
    int*   ge     = gs + NGRAPH;
    float* bnstat4 = (float*)(deg + 2 * NNODES + 128);
    int*   chunk  = (int*)alloc(NNODES * 4);
    int*   bsum   = (int*)alloc(128 * 4);
    int*   offs   = (int*)alloc((NNODES + 1) * 4);
    int*   csrsrc = (int*)alloc(NEDGES * 4);

    unsigned short* WtQKVS = WtAll;                      // [3][512][KC] q|k|v|s
    unsigned short* Wpt    = WtAll + (size_t)1536 * KC;
    unsigned short* Wt3    = WtAll + (size_t)1664 * KC;  // [1152][KC] t|s3
    float* bQKVS = bcat;          // [3][512]
    float* b3    = bcat + 1536;   // [1152] t|s3
    unsigned short* qkvs = tbuf;  // layers 0-2 alias: [N][512]

    const int TB = 256;
    const int ZWORDS = 2 * NNODES + 128 + 4 * 256;
    zero_kernel<<<(ZWORDS + TB - 1) / TB, TB, 0, stream>>>((float*)deg, ZWORDS);
    count_deg_kernel<<<(NEDGES + TB - 1) / TB, TB, 0, stream>>>(edst, deg, NEDGES);
    const int NB = (NNODES + 255) / 256;
    scan1_kernel<<<NB, 256, 0, stream>>>(deg, chunk, bsum, NNODES);
    scan2_kernel<<<1, 128, 0, stream>>>(bsum, NB);
    scan3_kernel<<<NB, 256, 0, stream>>>(chunk, bsum, offs, NNODES);
    scatter_gb_kernel<<<(NEDGES + TB - 1) / TB, TB, 0, stream>>>(
        esrc, edst, offs, cursor, csrsrc, NEDGES, batch, gs, ge, NNODES);

    prep_all_kernel<<<3989, 128, 0, stream>>>(Wq, Wk, Wv, Ws, Wp, Ws3,
                                              bq, bk, bv, bs, bs3,
                                              Wq3, Wk3, bq3, Wv3, bv3,
                                              WtAll, bcat, Wvm, bvm);

    const int CATB = (NPAD * HIDDIM + TB - 1) / TB;
    const int GSW = 8 * ((GXTILES + 7) / 8);  // 160 swizzled x-slots

    cat_from_kernel<<<CATB, TB, 0, stream>>>(x, Acat);
    // initial projection, epilogue writes Acat format in place (BY=1: block
    // bx reads only its own 128 rows, writes only those rows — race-free)
    gemm_lds_kernel<unsigned short, 12, 1, KC, 2><<<GSW * 1, 256, 0, stream>>>(
        Acat, Wpt, bp, Acat, 0, NNODES);

    for (int li = 0; li < 3; ++li) {
        gemm_lds_kernel<unsigned short, 8, 4, KC, 1><<<GSW * 4, 256, 0, stream>>>(
            Acat, WtQKVS + (size_t)li * 512 * KC, bQKVS + li * 512, qkvs, 512, NNODES);
        float* st = bnstat4 + li * 256;
        attn_small_kernel<<<NNODES / 4, 256, 0, stream>>>(qkvs, Wbeta + li * 384,
                                                          offs, csrsrc, obuf, st);
        bn_apply_kernel<<<512, 128, 0, stream>>>(obuf, st, bn_gamma + li * HIDDIM,
                                                 bn_beta + li * HIDDIM, NNODES, Acat);
    }

    // ---- layer 3: t|s GEMM -> fused 8-head aggregate -> mean-V GEMM ->
    //      beta+stats (also zeroes pool out) -> 16-way pool with fused BN ----
    gemm_lds_kernel<unsigned short, 8, 9, KC, 1><<<GSW * 9, 256, 0, stream>>>(
        Acat, Wt3, b3, tbuf, 1152, NNODES);
    attn_big_kernel<<<NNODES / 4, 256, 0, stream>>>(tbuf, Acat, offs, csrsrc, aggb);
    gemm_lds_kernel<float, 32, 1, 1024, 0><<<GSW, 256, 0, stream>>>(
        aggb, Wvm, bvm, omean, HIDDIM, NNODES);
    float* st3 = bnstat4 + 3 * 256;
    beta3_stats_kernel<<<512, 128, 0, stream>>>(omean, tbuf, Wbeta3, hbuf, st3, NNODES, out);
    pool_bn_part_kernel<<<dim3(NGRAPH, 8), 256, 0, stream>>>(
        hbuf, st3, bn_gamma + 3 * HIDDIM, bn_beta + 3 * HIDDIM, gs, ge, out, NNODES);
}

// Round 8
// 677.472 us; speedup vs baseline: 1.1472x; 1.1472x over previous
//
#include <hip/hip_runtime.h>
#include <math.h>

#define NNODES 20000
#define NPAD   20096   // 157 * 128
#define NEDGES 160000
#define HIDDIM 128
#define NHEADS 8
#define NGRAPH 64
#define KC 384   // concatenated K (hi | lo | hi)
#define GXTILES 157
#define NBUCKET 64

typedef short short8 __attribute__((ext_vector_type(8)));
typedef float floatx4 __attribute__((ext_vector_type(4)));
typedef unsigned short ushort4v __attribute__((ext_vector_type(4)));

__device__ inline unsigned short f2bf(float x) {
    unsigned u = __float_as_uint(x);
    u += 0x7fff + ((u >> 16) & 1);
    return (unsigned short)(u >> 16);
}
__device__ inline float bf2f(unsigned short h) {
    return __uint_as_float(((unsigned)h) << 16);
}

// async global->LDS DMA, 16B per lane (HW: lds dst = uniform base + lane*16)
__device__ __forceinline__ void gload16(const unsigned short* g, unsigned short* l) {
    __builtin_amdgcn_global_load_lds(
        (const __attribute__((address_space(1))) unsigned int*)g,
        (__attribute__((address_space(3))) unsigned int*)l, 16, 0, 0);
}

// ---------------- utility ----------------
__global__ __launch_bounds__(256) void zero_kernel(float* __restrict__ p, int n) {
    int i = blockIdx.x * blockDim.x + threadIdx.x;
    if (i < n) p[i] = 0.f;
}

// ---------------- CSR build ----------------
__global__ __launch_bounds__(256) void count_deg_kernel(const int* __restrict__ dst,
                                                        int* __restrict__ deg, int e) {
    int i = blockIdx.x * blockDim.x + threadIdx.x;
    if (i < e) atomicAdd(&deg[dst[i]], 1);
}

__global__ __launch_bounds__(256) void scan1_kernel(const int* __restrict__ deg,
                                                    int* __restrict__ chunk,
                                                    int* __restrict__ bsum, int n) {
    __shared__ int buf[256];
    int t = threadIdx.x;
    int i = blockIdx.x * 256 + t;
    int v = (i < n) ? deg[i] : 0;
    buf[t] = v;
    __syncthreads();
    for (int off = 1; off < 256; off <<= 1) {
        int tmp = (t >= off) ? buf[t - off] : 0;
        __syncthreads();
        buf[t] += tmp;
        __syncthreads();
    }
    if (i < n) chunk[i] = buf[t];
    if (t == 255) bsum[blockIdx.x] = buf[255];
}

__global__ __launch_bounds__(128) void scan2_kernel(int* __restrict__ bsum, int nb) {
    __shared__ int buf[128];
    int t = threadIdx.x;
    int v = (t < nb) ? bsum[t] : 0;
    buf[t] = v;
    __syncthreads();
    for (int off = 1; off < 128; off <<= 1) {
        int tmp = (t >= off) ? buf[t - off] : 0;
        __syncthreads();
        buf[t] += tmp;
        __syncthreads();
    }
    if (t < nb) bsum[t] = buf[t] - v;
}

__global__ __launch_bounds__(256) void scan3_kernel(const int* __restrict__ chunk,
                                                    const int* __restrict__ bsum,
                                                    int* __restrict__ offs, int n) {
    int i = blockIdx.x * 256 + threadIdx.x;
    if (i < n) offs[i + 1] = chunk[i] + bsum[i >> 8];
    if (i == 0) offs[0] = 0;
}

// scatter (edges) + graph-boundary detection (nodes) fused: one dispatch
__global__ __launch_bounds__(256) void scatter_gb_kernel(
    const int* __restrict__ src, const int* __restrict__ dst,
    const int* __restrict__ offs, int* __restrict__ cursor,
    int* __restrict__ csr_src, int e,
    const int* __restrict__ batch, int* __restrict__ gs, int* __restrict__ ge, int n) {
    int i = blockIdx.x * blockDim.x + threadIdx.x;
    if (i < e) {
        int d = dst[i];
        int pos = offs[d] + atomicAdd(&cursor[d], 1);
        csr_src[pos] = src[i];
    }
    if (i < n) {
        int b = batch[i];
        if (i == 0 || batch[i - 1] != b) gs[b] = i;
        if (i == n - 1 || batch[i + 1] != b) ge[b] = i + 1;
    }
}

// ---------------- ALL weight prep in one dispatch ----------------
// Blocks [0,1536): layers 0-2 q|k|v|s rows; [1536,1664): Wp rows;
// [1664,2688): skip (t rows, filled below); [2688,2816): Ws3 rows;
// [2816,2837): bias entries; [2837,3861): mqk t rows; [3861,3989): Wvm rows.
__global__ __launch_bounds__(128) void prep_all_kernel(
    const float* __restrict__ Wq, const float* __restrict__ Wk,
    const float* __restrict__ Wv, const float* __restrict__ Ws,
    const float* __restrict__ Wp, const float* __restrict__ Ws3,
    const float* __restrict__ bq, const float* __restrict__ bk,
    const float* __restrict__ bv, const float* __restrict__ bs,
    const float* __restrict__ bs3,
    const float* __restrict__ Wq3, const float* __restrict__ Wk3,
    const float* __restrict__ bq3,
    const float* __restrict__ Wv3, const float* __restrict__ bv3,
    unsigned short* __restrict__ WtAll, float* __restrict__ bcat,
    unsigned short* __restrict__ Wvm, float* __restrict__ bvm) {
    int id = blockIdx.x;
    int k = threadIdx.x;
    if (id >= 3861) {  // Wvm rows
        int j = id - 3861;
#pragma unroll
        for (int h = 0; h < 8; ++h) {
            float w = Wv3[(size_t)k * 1024 + h * 128 + j] * 0.125f;
            Wvm[(size_t)j * 1024 + h * 128 + k] = f2bf(w);
        }
        if (k == 0) {
            float s = 0.f;
            for (int h = 0; h < 8; ++h) s += bv3[h * 128 + j];
            bvm[j] = s * 0.125f;
        }
        return;
    }
    if (id >= 2837) {  // mqk t rows: M_h = Wq_h Wk_h^T
        int hb = id - 2837;
        int h = hb >> 7, b = hb & 127;
        __shared__ float wk[128];
        wk[k] = Wk3[(size_t)b * 1024 + h * 128 + k];
        __syncthreads();
        const float* wq = Wq3 + (size_t)k * 1024 + h * 128;
        float acc = 0.f;
#pragma unroll 16
        for (int d = 0; d < 128; ++d) acc = fmaf(wq[d], wk[d], acc);
        unsigned short hi = f2bf(acc);
        unsigned short lo = f2bf(acc - bf2f(hi));
        unsigned short* dst = WtAll + (size_t)(1664 + h * 128 + b) * KC;
        dst[k] = hi;
        dst[128 + k] = hi;
        dst[256 + k] = lo;
        if (k == 0) {
            float bb = 0.f;
            for (int d = 0; d < 128; ++d) bb = fmaf(bq3[h * 128 + d], wk[d], bb);
            bcat[1536 + h * 128 + b] = bb;
        }
        return;
    }
    if (id >= 2816) {  // bias
        int idx = (id - 2816) * 128 + k;
        if (idx >= 2688) return;
        float v;
        if (idx < 1536) {
            int li = idx / 512, n = idx % 512, sel = n >> 7, np = n & 127;
            const float* b = (sel == 0) ? bq : (sel == 1) ? bk : (sel == 2) ? bv : bs;
            v = b[li * 128 + np];
        } else if (idx < 2560) {
            return;  // t bias filled above
        } else {
            v = bs3[idx - 2560];
        }
        bcat[idx] = v;
        return;
    }
    float w;
    if (id < 1536) {
        int li = id / 512, n = id % 512, sel = n >> 7, np = n & 127;
        const float* W = (sel == 0) ? Wq : (sel == 1) ? Wk : (sel == 2) ? Wv : Ws;
        w = W[li * 16384 + k * 128 + np];
    } else if (id < 1664) {
        w = Wp[k * 128 + (id - 1536)];
    } else if (id < 2688) {
        return;  // t rows handled by mqk branch
    } else {
        w = Ws3[k * 128 + (id - 2688)];
    }
    unsigned short hi = f2bf(w);
    unsigned short lo = f2bf(w - bf2f(hi));
    unsigned short* dst = WtAll + (size_t)id * KC;
    dst[k] = hi;
    dst[128 + k] = hi;
    dst[256 + k] = lo;
}

// ---------------- activation -> split-bf16 A_cat ----------------
__global__ __launch_bounds__(256) void cat_from_kernel(const float* __restrict__ h,
                                                       unsigned short* __restrict__ Acat) {
    int idx = blockIdx.x * 256 + threadIdx.x;
    if (idx >= NPAD * HIDDIM) return;
    int r = idx >> 7, k = idx & 127;
    float x = (r < NNODES) ? h[idx] : 0.f;
    unsigned short hi = f2bf(x);
    unsigned short lo = f2bf(x - bf2f(hi));
    unsigned short* row = Acat + (size_t)r * KC;
    row[k] = hi;
    row[128 + k] = lo;
    row[256 + k] = hi;
}

// ---------------- LDS-staged MFMA GEMM (XCD swizzle, global_load_lds) ----------------
// Tile: 128 nodes x 128 feats per block, 4 waves. BK=32 double-buffered LDS
// (32KB), staging via global_load_lds width 16. Chunk-XOR swizzle on BOTH
// the pre-swizzled global source and the ds_read address (rule 21).
// OMODE: 0 = f32 out (stride M), 1 = bf16 out (stride M),
//        2 = Acat hi|lo|hi out (stride KC; safe in-place for BY=1).
template <typename OutT, int KG, int BY, int ST, int OMODE>
__global__ __launch_bounds__(256) void gemm_lds_kernel(
    const unsigned short* __restrict__ A, const unsigned short* __restrict__ Wt,
    const float* __restrict__ bias, OutT* __restrict__ C, int M, int nrows) {
    int id = blockIdx.x;
    int xcd = id & 7;
    int idx = id >> 3;
    int bx = (idx / BY) * 8 + xcd;
    int by = idx % BY;
    if (bx >= GXTILES) return;

    __shared__ unsigned short lds[2][2][4096];  // [buf][A/W][128 rows * 32 shorts]

    int tid = threadIdx.x;
    int lane = tid & 63;
    int wave = tid >> 6;
    int m = lane & 15;
    int q = lane >> 4;
    int nodeBase = bx * 128 + (wave & 1) * 64;
    int featBase = by * 128 + (wave >> 1) * 64;

    const unsigned short* gA = A + (size_t)bx * 128 * ST;
    const unsigned short* gW = Wt + (size_t)by * 128 * ST;

    int rs = lane >> 2;
    int cp0 = lane & 3;

    auto stagef = [&](int buf, int kk) {
        int kof = kk * 32;
#pragma unroll
        for (int jj = 0; jj < 2; ++jj) {
            int j = wave * 2 + jj;
            int row = j * 16 + rs;
            int g = cp0 ^ ((row >> 1) & 3);
            gload16(gA + (size_t)row * ST + kof + g * 8,
                    &lds[buf][0][0] + (size_t)j * 512);
            gload16(gW + (size_t)row * ST + kof + g * 8,
                    &lds[buf][1][0] + (size_t)j * 512);
        }
    };

    floatx4 acc[4][4];
#pragma unroll
    for (int r = 0; r < 4; ++r)
#pragma unroll
        for (int c = 0; c < 4; ++c) acc[r][c] = (floatx4){0.f, 0.f, 0.f, 0.f};

    stagef(0, 0);
    __syncthreads();

    for (int kg = 0; kg < KG; ++kg) {
        int cur = kg & 1;
        if (kg + 1 < KG) stagef(cur ^ 1, kg + 1);
        short8 a[4], b[4];
#pragma unroll
        for (int r = 0; r < 4; ++r) {
            int wr = (wave >> 1) * 64 + r * 16 + m;
            int cp = q ^ ((wr >> 1) & 3);
            a[r] = *(const short8*)(&lds[cur][1][0] + wr * 32 + cp * 8);
        }
#pragma unroll
        for (int c = 0; c < 4; ++c) {
            int ar = (wave & 1) * 64 + c * 16 + m;
            int cp = q ^ ((ar >> 1) & 3);
            b[c] = *(const short8*)(&lds[cur][0][0] + ar * 32 + cp * 8);
        }
#pragma unroll
        for (int r = 0; r < 4; ++r)
#pragma unroll
            for (int c = 0; c < 4; ++c)
                acc[r][c] = __builtin_amdgcn_mfma_f32_16x16x32_bf16(a[r], b[c], acc[r][c], 0, 0, 0);
        __syncthreads();
    }

    float4 bv[4];
#pragma unroll
    for (int r = 0; r < 4; ++r) bv[r] = *(const float4*)(bias + featBase + r * 16 + q * 4);
#pragma unroll
    for (int c = 0; c < 4; ++c) {
        int node = nodeBase + c * 16 + m;
        if (node < nrows) {
#pragma unroll
            for (int r = 0; r < 4; ++r) {
                int f0 = featBase + r * 16 + q * 4;
                float v0 = acc[r][c][0] + bv[r].x;
                float v1 = acc[r][c][1] + bv[r].y;
                float v2 = acc[r][c][2] + bv[r].z;
                float v3 = acc[r][c][3] + bv[r].w;
                if (OMODE == 2) {
                    unsigned short* row = (unsigned short*)C + (size_t)node * KC;
                    unsigned short h0 = f2bf(v0), h1 = f2bf(v1), h2 = f2bf(v2), h3 = f2bf(v3);
                    ushort4v hiv = {h0, h1, h2, h3};
                    ushort4v lov = {f2bf(v0 - bf2f(h0)), f2bf(v1 - bf2f(h1)),
                                    f2bf(v2 - bf2f(h2)), f2bf(v3 - bf2f(h3))};
                    *(ushort4v*)(row + f0) = hiv;
                    *(ushort4v*)(row + 128 + f0) = lov;
                    *(ushort4v*)(row + 256 + f0) = hiv;
                } else if (OMODE == 1) {
                    ushort4v o = {f2bf(v0), f2bf(v1), f2bf(v2), f2bf(v3)};
                    *(ushort4v*)((unsigned short*)C + (size_t)node * M + f0) = o;
                } else {
                    float4 o = {v0, v1, v2, v3};
                    *(float4*)((float*)C + (size_t)node * M + f0) = o;
                }
            }
        }
    }
}

// ---------------- attention layers 0-2 (pipelined; bucketed BN-stats) ----------------
// 64-thread blocks (one node/block, as in the 486us version). After the
// gated output, g==0 lanes atomicAdd their 4 features' sum/sq into bucket
// (blockIdx & 63) of statp — 20000/64 = 312 same-address adds per bucket
// slot (vs 5000 unbucketed, which serialized into ~125us).
__global__ __launch_bounds__(64) void attn_small_kernel(
    const unsigned short* __restrict__ qkvs,
    const float* __restrict__ Wb,
    const int* __restrict__ offs, const int* __restrict__ csr_src,
    float* __restrict__ out, float* __restrict__ statp) {
    int i = blockIdx.x;
    int l = threadIdx.x;
    int g = l >> 5;
    int d0 = (l & 31) * 4;
    uint2 qraw = *(const uint2*)(qkvs + (size_t)i * 512 + d0);
    uint2 rraw = *(const uint2*)(qkvs + (size_t)i * 512 + 384 + d0);
    float q0 = bf2f((unsigned short)(qraw.x & 0xffff)), q1 = bf2f((unsigned short)(qraw.x >> 16));
    float q2 = bf2f((unsigned short)(qraw.y & 0xffff)), q3 = bf2f((unsigned short)(qraw.y >> 16));
    int e0 = offs[i], e1 = offs[i + 1];
    float lac = 0.f;
    float a0 = 0.f, a1 = 0.f, a2 = 0.f, a3 = 0.f;
    int e = e0 + g;
    uint2 kk_n = {0, 0}, vv_n = {0, 0};
    if (e < e1) {
        int sn = csr_src[e];
        const unsigned short* row = qkvs + (size_t)sn * 512;
        kk_n = *(const uint2*)(row + 128 + d0);
        vv_n = *(const uint2*)(row + 256 + d0);
    }
    while (e < e1) {
        uint2 kk = kk_n, vv = vv_n;
        int en = e + 2;
        if (en < e1) {
            int sn2 = csr_src[en];
            const unsigned short* row2 = qkvs + (size_t)sn2 * 512;
            kk_n = *(const uint2*)(row2 + 128 + d0);
            vv_n = *(const uint2*)(row2 + 256 + d0);
        }
        float k0 = bf2f((unsigned short)(kk.x & 0xffff)), k1 = bf2f((unsigned short)(kk.x >> 16));
        float k2 = bf2f((unsigned short)(kk.y & 0xffff)), k3 = bf2f((unsigned short)(kk.y >> 16));
        float p = q0 * k0 + q1 * k1 + q2 * k2 + q3 * k3;
        p += __shfl_xor(p, 1);
        p += __shfl_xor(p, 2);
        float w = __expf(p * 0.25f);
        float v0 = bf2f((unsigned short)(vv.x & 0xffff)), v1 = bf2f((unsigned short)(vv.x >> 16));
        float v2 = bf2f((unsigned short)(vv.y & 0xffff)), v3 = bf2f((unsigned short)(vv.y >> 16));
        a0 += w * v0;
        a1 += w * v1;
        a2 += w * v2;
        a3 += w * v3;
        lac += w;
        e = en;
    }
    a0 += __shfl_xor(a0, 32);
    a1 += __shfl_xor(a1, 32);
    a2 += __shfl_xor(a2, 32);
    a3 += __shfl_xor(a3, 32);
    lac += __shfl_xor(lac, 32);
    float inv = 1.f / (lac + 1e-16f);
    float o0 = a0 * inv, o1 = a1 * inv, o2 = a2 * inv, o3 = a3 * inv;
    float r0 = bf2f((unsigned short)(rraw.x & 0xffff)), r1 = bf2f((unsigned short)(rraw.x >> 16));
    float r2 = bf2f((unsigned short)(rraw.y & 0xffff)), r3 = bf2f((unsigned short)(rraw.y >> 16));
    float part = o0 * Wb[d0] + o1 * Wb[d0 + 1] + o2 * Wb[d0 + 2] + o3 * Wb[d0 + 3]
               + r0 * Wb[128 + d0] + r1 * Wb[128 + d0 + 1]
               + r2 * Wb[128 + d0 + 2] + r3 * Wb[128 + d0 + 3]
               + (o0 - r0) * Wb[256 + d0] + (o1 - r1) * Wb[256 + d0 + 1]
               + (o2 - r2) * Wb[256 + d0 + 2] + (o3 - r3) * Wb[256 + d0 + 3];
    if (g) part = 0.f;
#pragma unroll
    for (int msk = 1; msk <= 32; msk <<= 1) part += __shfl_xor(part, msk);
    float gg = 1.f / (1.f + __expf(-part));
    if (g == 0) {
        float w0 = gg * r0 + (1.f - gg) * o0;
        float w1 = gg * r1 + (1.f - gg) * o1;
        float w2 = gg * r2 + (1.f - gg) * o2;
        float w3 = gg * r3 + (1.f - gg) * o3;
        float4 o4 = {w0, w1, w2, w3};
        *(float4*)(out + (size_t)i * HIDDIM + d0) = o4;
        float* sp = statp + (size_t)(i & (NBUCKET - 1)) * 256;
        atomicAdd(&sp[d0], w0);           atomicAdd(&sp[128 + d0], w0 * w0);
        atomicAdd(&sp[d0 + 1], w1);       atomicAdd(&sp[128 + d0 + 1], w1 * w1);
        atomicAdd(&sp[d0 + 2], w2);       atomicAdd(&sp[128 + d0 + 2], w2 * w2);
        atomicAdd(&sp[d0 + 3], w3);       atomicAdd(&sp[128 + d0 + 3], w3 * w3);
    }
}

// ---------------- attention layer 3 (pipelined, 64-thread blocks) ----------------
// t node-major [N][1152] (t at 0, s at 1024). agg node-major [N][1024] bf16.
__global__ __launch_bounds__(64) void attn_big_kernel(
    const unsigned short* __restrict__ tbuf, const unsigned short* __restrict__ Acat,
    const int* __restrict__ offs, const int* __restrict__ csr_src,
    unsigned short* __restrict__ agg) {
    int i = blockIdx.x;
    int l = threadIdx.x;
    int doff = (l & 7) * 16;
    const unsigned short* tp = tbuf + (size_t)i * 1152 + l * 16;
    uint4 t0 = *(const uint4*)tp;
    uint4 t1 = *(const uint4*)(tp + 8);
    float tq[16];
    tq[0] = bf2f((unsigned short)(t0.x & 0xffff)); tq[1] = bf2f((unsigned short)(t0.x >> 16));
    tq[2] = bf2f((unsigned short)(t0.y & 0xffff)); tq[3] = bf2f((unsigned short)(t0.y >> 16));
    tq[4] = bf2f((unsigned short)(t0.z & 0xffff)); tq[5] = bf2f((unsigned short)(t0.z >> 16));
    tq[6] = bf2f((unsigned short)(t0.w & 0xffff)); tq[7] = bf2f((unsigned short)(t0.w >> 16));
    tq[8] = bf2f((unsigned short)(t1.x & 0xffff)); tq[9] = bf2f((unsigned short)(t1.x >> 16));
    tq[10] = bf2f((unsigned short)(t1.y & 0xffff)); tq[11] = bf2f((unsigned short)(t1.y >> 16));
    tq[12] = bf2f((unsigned short)(t1.z & 0xffff)); tq[13] = bf2f((unsigned short)(t1.z >> 16));
    tq[14] = bf2f((unsigned short)(t1.w & 0xffff)); tq[15] = bf2f((unsigned short)(t1.w >> 16));
    int e0 = offs[i], e1 = offs[i + 1];
    float ac[16];
#pragma unroll
    for (int j = 0; j < 16; ++j) ac[j] = 0.f;
    float lac = 0.f;
    int e = e0;
    uint4 k0n = {0, 0, 0, 0}, k1n = {0, 0, 0, 0};
    if (e < e1) {
        const unsigned short* hp = Acat + (size_t)csr_src[e] * KC + doff;
        k0n = *(const uint4*)hp;
        k1n = *(const uint4*)(hp + 8);
    }
    while (e < e1) {
        uint4 k0 = k0n, k1 = k1n;
        int en = e + 1;
        if (en < e1) {
            const unsigned short* hp2 = Acat + (size_t)csr_src[en] * KC + doff;
            k0n = *(const uint4*)hp2;
            k1n = *(const uint4*)(hp2 + 8);
        }
        float kk[16];
        kk[0] = bf2f((unsigned short)(k0.x & 0xffff)); kk[1] = bf2f((unsigned short)(k0.x >> 16));
        kk[2] = bf2f((unsigned short)(k0.y & 0xffff)); kk[3] = bf2f((unsigned short)(k0.y >> 16));
        kk[4] = bf2f((unsigned short)(k0.z & 0xffff)); kk[5] = bf2f((unsigned short)(k0.z >> 16));
        kk[6] = bf2f((unsigned short)(k0.w & 0xffff)); kk[7] = bf2f((unsigned short)(k0.w >> 16));
        kk[8] = bf2f((unsigned short)(k1.x & 0xffff)); kk[9] = bf2f((unsigned short)(k1.x >> 16));
        kk[10] = bf2f((unsigned short)(k1.y & 0xffff)); kk[11] = bf2f((unsigned short)(k1.y >> 16));
        kk[12] = bf2f((unsigned short)(k1.z & 0xffff)); kk[13] = bf2f((unsigned short)(k1.z >> 16));
        kk[14] = bf2f((unsigned short)(k1.w & 0xffff)); kk[15] = bf2f((unsigned short)(k1.w >> 16));
        float p = 0.f;
#pragma unroll
        for (int j = 0; j < 16; ++j) p = fmaf(tq[j], kk[j], p);
        p += __shfl_xor(p, 1);
        p += __shfl_xor(p, 2);
        p += __shfl_xor(p, 4);
        float w = __expf(p * 0.08838834764831845f);
#pragma unroll
        for (int j = 0; j < 16; ++j) ac[j] = fmaf(w, kk[j], ac[j]);
        lac += w;
        e = en;
    }
    float inv = 1.f / (lac + 1e-16f);
    unsigned short* o = agg + (size_t)i * 1024 + l * 16;
    ushort4v o0 = {f2bf(ac[0] * inv), f2bf(ac[1] * inv), f2bf(ac[2] * inv), f2bf(ac[3] * inv)};
    ushort4v o1 = {f2bf(ac[4] * inv), f2bf(ac[5] * inv), f2bf(ac[6] * inv), f2bf(ac[7] * inv)};
    ushort4v o2 = {f2bf(ac[8] * inv), f2bf(ac[9] * inv), f2bf(ac[10] * inv), f2bf(ac[11] * inv)};
    ushort4v o3 = {f2bf(ac[12] * inv), f2bf(ac[13] * inv), f2bf(ac[14] * inv), f2bf(ac[15] * inv)};
    *(ushort4v*)o = o0;
    *(ushort4v*)(o + 4) = o1;
    *(ushort4v*)(o + 8) = o2;
    *(ushort4v*)(o + 12) = o3;
}

// ---------------- beta gate layer 3 + BN stats, fused (grid-stride) ----------------
// Also zeroes the 64x128 pool output (blocks 0..63).
__global__ __launch_bounds__(128) void beta3_stats_kernel(
    const float* __restrict__ omean, const unsigned short* __restrict__ tbuf,
    const float* __restrict__ Wb, float* __restrict__ out,
    float* __restrict__ stat, int n, float* __restrict__ pool_out) {
    int t = threadIdx.x;
    if (blockIdx.x < NGRAPH) pool_out[blockIdx.x * HIDDIM + t] = 0.f;
    __shared__ float wsum[2];
    float s = 0.f, sq = 0.f;
    for (int i = blockIdx.x; i < n; i += gridDim.x) {
        float o = omean[(size_t)i * HIDDIM + t];
        float r = bf2f(tbuf[(size_t)i * 1152 + 1024 + t]);
        float part = o * Wb[t] + r * Wb[128 + t] + (o - r) * Wb[256 + t];
#pragma unroll
        for (int msk = 1; msk <= 32; msk <<= 1) part += __shfl_xor(part, msk);
        if ((t & 63) == 0) wsum[t >> 6] = part;
        __syncthreads();
        float tot = wsum[0] + wsum[1];
        __syncthreads();
        float g = 1.f / (1.f + __expf(-tot));
        float v = g * r + (1.f - g) * o;
        out[(size_t)i * HIDDIM + t] = v;
        s += v;
        sq += v * v;
    }
    atomicAdd(&stat[t], s);
    atomicAdd(&stat[HIDDIM + t], sq);
}

// ---------------- batchnorm apply (layers 0-2): sums 64 buckets, applies ----------------
__global__ __launch_bounds__(128) void bn_apply_kernel(float* __restrict__ x,
                                                       const float* __restrict__ statp,
                                                       const float* __restrict__ gamma,
                                                       const float* __restrict__ beta, int n,
                                                       unsigned short* __restrict__ cat) {
    int t = threadIdx.x;
    float s = 0.f, sq = 0.f;
    for (int b = 0; b < NBUCKET; ++b) {
        s += statp[(size_t)b * 256 + t];
        sq += statp[(size_t)b * 256 + 128 + t];
    }
    float mu = s / (float)n;
    float var = sq / (float)n - mu * mu;
    float rs = rsqrtf(var + 1e-5f);
    float g = gamma[t], b = beta[t];
    for (int i = blockIdx.x; i < n; i += gridDim.x) {
        float v = x[(size_t)i * HIDDIM + t];
        v = fmaxf((v - mu) * rs * g + b, 0.f);
        x[(size_t)i * HIDDIM + t] = v;
        if (cat) {
            unsigned short hi = f2bf(v);
            unsigned short lo = f2bf(v - bf2f(hi));
            unsigned short* row = cat + (size_t)i * KC;
            row[t] = hi;
            row[128 + t] = lo;
            row[256 + t] = hi;
        }
    }
}

// ---------------- pool: fused BN+ReLU+mean, 16-way parallel partials ----------------
__global__ __launch_bounds__(256) void pool_bn_part_kernel(
    const float* __restrict__ x, const float* __restrict__ stat,
    const float* __restrict__ gamma, const float* __restrict__ beta,
    const int* __restrict__ gs, const int* __restrict__ ge,
    float* __restrict__ out, int n) {
    int g = blockIdx.x, c = blockIdx.y;
    int t = threadIdx.x;
    int f = t & 127, half = t >> 7;
    float mu = stat[f] / (float)n;
    float var = stat[HIDDIM + f] / (float)n - mu * mu;
    float rs = rsqrtf(var + 1e-5f);
    float ga = gamma[f], be = beta[f];
    int s = gs[g], e = ge[g];
    float acc = 0.f;
    for (int i = s + 2 * c + half; i < e; i += 16)
        acc += fmaxf((x[(size_t)i * HIDDIM + f] - mu) * rs * ga + be, 0.f);
    __shared__ float l0[128];
    if (half == 0) l0[f] = acc;
    __syncthreads();
    if (half == 1) {
        int cnt = e - s;
        float inv = 1.f / (float)(cnt > 0 ? cnt : 1);
        atomicAdd(&out[g * HIDDIM + f], (l0[f] + acc) * inv);
    }
}

// ---------------- host ----------------
extern "C" void kernel_launch(void* const* d_in, const int* in_sizes, int n_in,
                              void* d_out, int out_size, void* d_ws, size_t ws_size,
                              hipStream_t stream) {
    const float* x       = (const float*)d_in[0];
    const int*   ei      = (const int*)d_in[1];
    const int*   batch   = (const int*)d_in[2];
    const float* Wp      = (const float*)d_in[3];
    const float* bp      = (const float*)d_in[4];
    const float* Wq      = (const float*)d_in[5];
    const float* bq      = (const float*)d_in[6];
    const float* Wk      = (const float*)d_in[7];
    const float* bk      = (const float*)d_in[8];
    const float* Wv      = (const float*)d_in[9];
    const float* bv      = (const float*)d_in[10];
    const float* Ws      = (const float*)d_in[11];
    const float* bs      = (const float*)d_in[12];
    const float* Wbeta   = (const float*)d_in[13];
    const float* Wq3     = (const float*)d_in[14];
    const float* bq3     = (const float*)d_in[15];
    const float* Wk3     = (const float*)d_in[16];
    const float* bk3     = (const float*)d_in[17];
    const float* Wv3     = (const float*)d_in[18];
    const float* bv3     = (const float*)d_in[19];
    const float* Ws3     = (const float*)d_in[20];
    const float* bs3     = (const float*)d_in[21];
    const float* Wbeta3  = (const float*)d_in[22];
    const float* bn_gamma = (const float*)d_in[23];
    const float* bn_beta  = (const float*)d_in[24];
    float* out = (float*)d_out;
    (void)bk3;

    const int* esrc = ei;
    const int* edst = ei + NEDGES;

    char* wpc = (char*)d_ws;
    auto alloc = [&](size_t nbytes) -> char* {
        char* p = wpc;
        wpc += (nbytes + 255) & ~(size_t)255;
        return p;
    };
    unsigned short* Acat  = (unsigned short*)alloc((size_t)NPAD * KC * 2);      // 15.4 MB
    unsigned short* WtAll = (unsigned short*)alloc((size_t)2816 * KC * 2);      // 2.2 MB
    float* bcat   = (float*)alloc(2688 * 4);
    unsigned short* Wvm   = (unsigned short*)alloc((size_t)128 * 1024 * 2);     // 256 KB
    float* bvm    = (float*)alloc(128 * 4);
    unsigned short* tbuf  = (unsigned short*)alloc((size_t)NPAD * 1152 * 2);    // 46.3 MB (alias qkvs)
    unsigned short* aggb  = (unsigned short*)alloc((size_t)NPAD * 1024 * 2);    // 41 MB
    float* omean  = (float*)alloc((size_t)NNODES * HIDDIM * 4);                 // 10.2 MB
    float* hbuf   = (float*)alloc((size_t)NNODES * HIDDIM * 4);
    float* obuf   = (float*)alloc((size_t)NNODES * HIDDIM * 4);
    // zeroed scratch: deg | cursor | gs/ge | bnstat4 | stat buckets (3 layers)
    const int ZWORDS = 2 * NNODES + 128 + 4 * 256 + 3 * NBUCKET * 256;
    int*   deg    = (int*)alloc((size_t)ZWORDS * 4);
    int*   cursor = deg + NNODES;
    int*   gs     = deg + 2 * NNODES;
    int*   ge     = gs + NGRAPH;
    float* bnstat4 = (float*)(deg + 2 * NNODES + 128);
    float* statp   = bnstat4 + 4 * 256;   // [3][NBUCKET][256]
    int*   chunk  = (int*)alloc(NNODES * 4);
    int*   bsum   = (int*)alloc(128 * 4);
    int*   offs   = (int*)alloc((NNODES + 1) * 4);
    int*   csrsrc = (int*)alloc(NEDGES * 4);

    unsigned short* WtQKVS = WtAll;                      // [3][512][KC] q|k|v|s
    unsigned short* Wpt    = WtAll + (size_t)1536 * KC;
    unsigned short* Wt3    = WtAll + (size_t)1664 * KC;  // [1152][KC] t|s3
    float* bQKVS = bcat;          // [3][512]
    float* b3    = bcat + 1536;   // [1152] t|s3
    unsigned short* qkvs = tbuf;  // layers 0-2 alias: [N][512]

    const int TB = 256;
    zero_kernel<<<(ZWORDS + TB - 1) / TB, TB, 0, stream>>>((float*)deg, ZWORDS);
    count_deg_kernel<<<(NEDGES + TB - 1) / TB, TB, 0, stream>>>(edst, deg, NEDGES);
    const int NB = (NNODES + 255) / 256;
    scan1_kernel<<<NB, 256, 0, stream>>>(deg, chunk, bsum, NNODES);
    scan2_kernel<<<1, 128, 0, stream>>>(bsum, NB);
    scan3_kernel<<<NB, 256, 0, stream>>>(chunk, bsum, offs, NNODES);
    scatter_gb_kernel<<<(NEDGES + TB - 1) / TB, TB, 0, stream>>>(
        esrc, edst, offs, cursor, csrsrc, NEDGES, batch, gs, ge, NNODES);

    prep_all_kernel<<<3989, 128, 0, stream>>>(Wq, Wk, Wv, Ws, Wp, Ws3,
                                              bq, bk, bv, bs, bs3,
                                              Wq3, Wk3, bq3, Wv3, bv3,
                                              WtAll, bcat, Wvm, bvm);

    const int CATB = (NPAD * HIDDIM + TB - 1) / TB;
    const int GSW = 8 * ((GXTILES + 7) / 8);  // 160 swizzled x-slots

    cat_from_kernel<<<CATB, TB, 0, stream>>>(x, Acat);
    // initial projection, epilogue writes Acat format in place (BY=1: block
    // bx reads only its own 128 rows, writes only those rows — race-free)
    gemm_lds_kernel<unsigned short, 12, 1, KC, 2><<<GSW * 1, 256, 0, stream>>>(
        Acat, Wpt, bp, Acat, 0, NNODES);

    for (int li = 0; li < 3; ++li) {
        gemm_lds_kernel<unsigned short, 8, 4, KC, 1><<<GSW * 4, 256, 0, stream>>>(
            Acat, WtQKVS + (size_t)li * 512 * KC, bQKVS + li * 512, qkvs, 512, NNODES);
        float* sp = statp + (size_t)li * NBUCKET * 256;
        attn_small_kernel<<<NNODES, 64, 0, stream>>>(qkvs, Wbeta + li * 384,
                                                     offs, csrsrc, obuf, sp);
        bn_apply_kernel<<<512, 128, 0, stream>>>(obuf, sp, bn_gamma + li * HIDDIM,
                                                 bn_beta + li * HIDDIM, NNODES, Acat);
    }

    // ---- layer 3: t|s GEMM -> fused 8-head aggregate -> mean-V GEMM ->
    //      beta+stats (also zeroes pool out) -> 16-way pool with fused BN ----
    gemm_lds_kernel<unsigned short, 8, 9, KC, 1><<<GSW * 9, 256, 0, stream>>>(
        Acat, Wt3, b3, tbuf, 1152, NNODES);
    attn_big_kernel<<<NNODES, 64, 0, stream>>>(tbuf, Acat, offs, csrsrc, aggb);
    gemm_lds_kernel<float, 32, 1, 1024, 0><<<GSW, 256, 0, stream>>>(
        aggb, Wvm, bvm, omean, HIDDIM, NNODES);
    float* st3 = bnstat4 + 3 * 256;
    beta3_stats_kernel<<<512, 128, 0, stream>>>(omean, tbuf, Wbeta3, hbuf, st3, NNODES, out);
    pool_bn_part_kernel<<<dim3(NGRAPH, 8), 256, 0, stream>>>(
        hbuf, st3, bn_gamma + 3 * HIDDIM, bn_beta + 3 * HIDDIM, gs, ge, out, NNODES);
}

// Round 9
// 484.717 us; speedup vs baseline: 1.6035x; 1.3977x over previous
//
#include <hip/hip_runtime.h>
#include <math.h>

#define NNODES 20000
#define NPAD   20096   // 157 * 128
#define NEDGES 160000
#define HIDDIM 128
#define NHEADS 8
#define NGRAPH 64
#define KC 384   // concatenated K (hi | lo | hi)
#define GXTILES 157

typedef short short8 __attribute__((ext_vector_type(8)));
typedef float floatx4 __attribute__((ext_vector_type(4)));
typedef unsigned short ushort4v __attribute__((ext_vector_type(4)));

__device__ inline unsigned short f2bf(float x) {
    unsigned u = __float_as_uint(x);
    u += 0x7fff + ((u >> 16) & 1);
    return (unsigned short)(u >> 16);
}
__device__ inline float bf2f(unsigned short h) {
    return __uint_as_float(((unsigned)h) << 16);
}

// async global->LDS DMA, 16B per lane (HW: lds dst = uniform base + lane*16)
__device__ __forceinline__ void gload16(const unsigned short* g, unsigned short* l) {
    __builtin_amdgcn_global_load_lds(
        (const __attribute__((address_space(1))) unsigned int*)g,
        (__attribute__((address_space(3))) unsigned int*)l, 16, 0, 0);
}

// ---------------- utility ----------------
__global__ __launch_bounds__(256) void zero_kernel(float* __restrict__ p, int n) {
    int i = blockIdx.x * blockDim.x + threadIdx.x;
    if (i < n) p[i] = 0.f;
}

// ---------------- CSR build ----------------
__global__ __launch_bounds__(256) void count_deg_kernel(const int* __restrict__ dst,
                                                        int* __restrict__ deg, int e) {
    int i = blockIdx.x * blockDim.x + threadIdx.x;
    if (i < e) atomicAdd(&deg[dst[i]], 1);
}

__global__ __launch_bounds__(256) void scan1_kernel(const int* __restrict__ deg,
                                                    int* __restrict__ chunk,
                                                    int* __restrict__ bsum, int n) {
    __shared__ int buf[256];
    int t = threadIdx.x;
    int i = blockIdx.x * 256 + t;
    int v = (i < n) ? deg[i] : 0;
    buf[t] = v;
    __syncthreads();
    for (int off = 1; off < 256; off <<= 1) {
        int tmp = (t >= off) ? buf[t - off] : 0;
        __syncthreads();
        buf[t] += tmp;
        __syncthreads();
    }
    if (i < n) chunk[i] = buf[t];
    if (t == 255) bsum[blockIdx.x] = buf[255];
}

__global__ __launch_bounds__(128) void scan2_kernel(int* __restrict__ bsum, int nb) {
    __shared__ int buf[128];
    int t = threadIdx.x;
    int v = (t < nb) ? bsum[t] : 0;
    buf[t] = v;
    __syncthreads();
    for (int off = 1; off < 128; off <<= 1) {
        int tmp = (t >= off) ? buf[t - off] : 0;
        __syncthreads();
        buf[t] += tmp;
        __syncthreads();
    }
    if (t < nb) bsum[t] = buf[t] - v;
}

__global__ __launch_bounds__(256) void scan3_kernel(const int* __restrict__ chunk,
                                                    const int* __restrict__ bsum,
                                                    int* __restrict__ offs, int n) {
    int i = blockIdx.x * 256 + threadIdx.x;
    if (i < n) offs[i + 1] = chunk[i] + bsum[i >> 8];
    if (i == 0) offs[0] = 0;
}

// scatter (edges) + graph-boundary detection (nodes) fused: one dispatch
__global__ __launch_bounds__(256) void scatter_gb_kernel(
    const int* __restrict__ src, const int* __restrict__ dst,
    const int* __restrict__ offs, int* __restrict__ cursor,
    int* __restrict__ csr_src, int e,
    const int* __restrict__ batch, int* __restrict__ gs, int* __restrict__ ge, int n) {
    int i = blockIdx.x * blockDim.x + threadIdx.x;
    if (i < e) {
        int d = dst[i];
        int pos = offs[d] + atomicAdd(&cursor[d], 1);
        csr_src[pos] = src[i];
    }
    if (i < n) {
        int b = batch[i];
        if (i == 0 || batch[i - 1] != b) gs[b] = i;
        if (i == n - 1 || batch[i + 1] != b) ge[b] = i + 1;
    }
}

// ---------------- ALL weight prep in one dispatch ----------------
// Blocks [0,1536): layers 0-2 q|k|v|s rows; [1536,1664): Wp rows;
// [1664,2688): skip (t rows, filled below); [2688,2816): Ws3 rows;
// [2816,2837): bias entries; [2837,3861): mqk t rows; [3861,3989): Wvm rows.
__global__ __launch_bounds__(128) void prep_all_kernel(
    const float* __restrict__ Wq, const float* __restrict__ Wk,
    const float* __restrict__ Wv, const float* __restrict__ Ws,
    const float* __restrict__ Wp, const float* __restrict__ Ws3,
    const float* __restrict__ bq, const float* __restrict__ bk,
    const float* __restrict__ bv, const float* __restrict__ bs,
    const float* __restrict__ bs3,
    const float* __restrict__ Wq3, const float* __restrict__ Wk3,
    const float* __restrict__ bq3,
    const float* __restrict__ Wv3, const float* __restrict__ bv3,
    unsigned short* __restrict__ WtAll, float* __restrict__ bcat,
    unsigned short* __restrict__ Wvm, float* __restrict__ bvm) {
    int id = blockIdx.x;
    int k = threadIdx.x;
    if (id >= 3861) {  // Wvm rows
        int j = id - 3861;
#pragma unroll
        for (int h = 0; h < 8; ++h) {
            float w = Wv3[(size_t)k * 1024 + h * 128 + j] * 0.125f;
            Wvm[(size_t)j * 1024 + h * 128 + k] = f2bf(w);
        }
        if (k == 0) {
            float s = 0.f;
            for (int h = 0; h < 8; ++h) s += bv3[h * 128 + j];
            bvm[j] = s * 0.125f;
        }
        return;
    }
    if (id >= 2837) {  // mqk t rows: M_h = Wq_h Wk_h^T
        int hb = id - 2837;
        int h = hb >> 7, b = hb & 127;
        __shared__ float wk[128];
        wk[k] = Wk3[(size_t)b * 1024 + h * 128 + k];
        __syncthreads();
        const float* wq = Wq3 + (size_t)k * 1024 + h * 128;
        float acc = 0.f;
#pragma unroll 16
        for (int d = 0; d < 128; ++d) acc = fmaf(wq[d], wk[d], acc);
        unsigned short hi = f2bf(acc);
        unsigned short lo = f2bf(acc - bf2f(hi));
        unsigned short* dst = WtAll + (size_t)(1664 + h * 128 + b) * KC;
        dst[k] = hi;
        dst[128 + k] = hi;
        dst[256 + k] = lo;
        if (k == 0) {
            float bb = 0.f;
            for (int d = 0; d < 128; ++d) bb = fmaf(bq3[h * 128 + d], wk[d], bb);
            bcat[1536 + h * 128 + b] = bb;
        }
        return;
    }
    if (id >= 2816) {  // bias
        int idx = (id - 2816) * 128 + k;
        if (idx >= 2688) return;
        float v;
        if (idx < 1536) {
            int li = idx / 512, n = idx % 512, sel = n >> 7, np = n & 127;
            const float* b = (sel == 0) ? bq : (sel == 1) ? bk : (sel == 2) ? bv : bs;
            v = b[li * 128 + np];
        } else if (idx < 2560) {
            return;  // t bias filled above
        } else {
            v = bs3[idx - 2560];
        }
        bcat[idx] = v;
        return;
    }
    float w;
    if (id < 1536) {
        int li = id / 512, n = id % 512, sel = n >> 7, np = n & 127;
        const float* W = (sel == 0) ? Wq : (sel == 1) ? Wk : (sel == 2) ? Wv : Ws;
        w = W[li * 16384 + k * 128 + np];
    } else if (id < 1664) {
        w = Wp[k * 128 + (id - 1536)];
    } else if (id < 2688) {
        return;  // t rows handled by mqk branch
    } else {
        w = Ws3[k * 128 + (id - 2688)];
    }
    unsigned short hi = f2bf(w);
    unsigned short lo = f2bf(w - bf2f(hi));
    unsigned short* dst = WtAll + (size_t)id * KC;
    dst[k] = hi;
    dst[128 + k] = hi;
    dst[256 + k] = lo;
}

// ---------------- activation -> split-bf16 A_cat ----------------
__global__ __launch_bounds__(256) void cat_from_kernel(const float* __restrict__ h,
                                                       unsigned short* __restrict__ Acat) {
    int idx = blockIdx.x * 256 + threadIdx.x;
    if (idx >= NPAD * HIDDIM) return;
    int r = idx >> 7, k = idx & 127;
    float x = (r < NNODES) ? h[idx] : 0.f;
    unsigned short hi = f2bf(x);
    unsigned short lo = f2bf(x - bf2f(hi));
    unsigned short* row = Acat + (size_t)r * KC;
    row[k] = hi;
    row[128 + k] = lo;
    row[256 + k] = hi;
}

// ---------------- LDS-staged MFMA GEMM (XCD swizzle, global_load_lds) ----------------
// Tile: 128 nodes x 128 feats per block, 4 waves. BK=32 double-buffered LDS
// (32KB), staging via global_load_lds width 16. Chunk-XOR swizzle on BOTH
// the pre-swizzled global source and the ds_read address (rule 21).
// OMODE: 0 = f32 out (stride M), 1 = bf16 out (stride M),
//        2 = Acat hi|lo|hi out (stride KC; safe in-place for BY=1).
template <typename OutT, int KG, int BY, int ST, int OMODE>
__global__ __launch_bounds__(256) void gemm_lds_kernel(
    const unsigned short* __restrict__ A, const unsigned short* __restrict__ Wt,
    const float* __restrict__ bias, OutT* __restrict__ C, int M, int nrows) {
    int id = blockIdx.x;
    int xcd = id & 7;
    int idx = id >> 3;
    int bx = (idx / BY) * 8 + xcd;
    int by = idx % BY;
    if (bx >= GXTILES) return;

    __shared__ unsigned short lds[2][2][4096];  // [buf][A/W][128 rows * 32 shorts]

    int tid = threadIdx.x;
    int lane = tid & 63;
    int wave = tid >> 6;
    int m = lane & 15;
    int q = lane >> 4;
    int nodeBase = bx * 128 + (wave & 1) * 64;
    int featBase = by * 128 + (wave >> 1) * 64;

    const unsigned short* gA = A + (size_t)bx * 128 * ST;
    const unsigned short* gW = Wt + (size_t)by * 128 * ST;

    int rs = lane >> 2;
    int cp0 = lane & 3;

    auto stagef = [&](int buf, int kk) {
        int kof = kk * 32;
#pragma unroll
        for (int jj = 0; jj < 2; ++jj) {
            int j = wave * 2 + jj;
            int row = j * 16 + rs;
            int g = cp0 ^ ((row >> 1) & 3);
            gload16(gA + (size_t)row * ST + kof + g * 8,
                    &lds[buf][0][0] + (size_t)j * 512);
            gload16(gW + (size_t)row * ST + kof + g * 8,
                    &lds[buf][1][0] + (size_t)j * 512);
        }
    };

    floatx4 acc[4][4];
#pragma unroll
    for (int r = 0; r < 4; ++r)
#pragma unroll
        for (int c = 0; c < 4; ++c) acc[r][c] = (floatx4){0.f, 0.f, 0.f, 0.f};

    stagef(0, 0);
    __syncthreads();

    for (int kg = 0; kg < KG; ++kg) {
        int cur = kg & 1;
        if (kg + 1 < KG) stagef(cur ^ 1, kg + 1);
        short8 a[4], b[4];
#pragma unroll
        for (int r = 0; r < 4; ++r) {
            int wr = (wave >> 1) * 64 + r * 16 + m;
            int cp = q ^ ((wr >> 1) & 3);
            a[r] = *(const short8*)(&lds[cur][1][0] + wr * 32 + cp * 8);
        }
#pragma unroll
        for (int c = 0; c < 4; ++c) {
            int ar = (wave & 1) * 64 + c * 16 + m;
            int cp = q ^ ((ar >> 1) & 3);
            b[c] = *(const short8*)(&lds[cur][0][0] + ar * 32 + cp * 8);
        }
#pragma unroll
        for (int r = 0; r < 4; ++r)
#pragma unroll
            for (int c = 0; c < 4; ++c)
                acc[r][c] = __builtin_amdgcn_mfma_f32_16x16x32_bf16(a[r], b[c], acc[r][c], 0, 0, 0);
        __syncthreads();
    }

    float4 bv[4];
#pragma unroll
    for (int r = 0; r < 4; ++r) bv[r] = *(const float4*)(bias + featBase + r * 16 + q * 4);
#pragma unroll
    for (int c = 0; c < 4; ++c) {
        int node = nodeBase + c * 16 + m;
        if (node < nrows) {
#pragma unroll
            for (int r = 0; r < 4; ++r) {
                int f0 = featBase + r * 16 + q * 4;
                float v0 = acc[r][c][0] + bv[r].x;
                float v1 = acc[r][c][1] + bv[r].y;
                float v2 = acc[r][c][2] + bv[r].z;
                float v3 = acc[r][c][3] + bv[r].w;
                if (OMODE == 2) {
                    unsigned short* row = (unsigned short*)C + (size_t)node * KC;
                    unsigned short h0 = f2bf(v0), h1 = f2bf(v1), h2 = f2bf(v2), h3 = f2bf(v3);
                    ushort4v hiv = {h0, h1, h2, h3};
                    ushort4v lov = {f2bf(v0 - bf2f(h0)), f2bf(v1 - bf2f(h1)),
                                    f2bf(v2 - bf2f(h2)), f2bf(v3 - bf2f(h3))};
                    *(ushort4v*)(row + f0) = hiv;
                    *(ushort4v*)(row + 128 + f0) = lov;
                    *(ushort4v*)(row + 256 + f0) = hiv;
                } else if (OMODE == 1) {
                    ushort4v o = {f2bf(v0), f2bf(v1), f2bf(v2), f2bf(v3)};
                    *(ushort4v*)((unsigned short*)C + (size_t)node * M + f0) = o;
                } else {
                    float4 o = {v0, v1, v2, v3};
                    *(float4*)((float*)C + (size_t)node * M + f0) = o;
                }
            }
        }
    }
}

// ---------------- attention layers 0-2 (depth-2 pipelined edge loop) ----------------
// Per lane-group g, edges go g, g+2, g+4...; two gathers kept in flight.
__global__ __launch_bounds__(64) void attn_small_kernel(
    const unsigned short* __restrict__ qkvs,
    const float* __restrict__ Wb,
    const int* __restrict__ offs, const int* __restrict__ csr_src,
    float* __restrict__ out) {
    int i = blockIdx.x;
    int l = threadIdx.x;
    int g = l >> 5;
    int d0 = (l & 31) * 4;
    uint2 qraw = *(const uint2*)(qkvs + (size_t)i * 512 + d0);
    uint2 rraw = *(const uint2*)(qkvs + (size_t)i * 512 + 384 + d0);
    float q0 = bf2f((unsigned short)(qraw.x & 0xffff)), q1 = bf2f((unsigned short)(qraw.x >> 16));
    float q2 = bf2f((unsigned short)(qraw.y & 0xffff)), q3 = bf2f((unsigned short)(qraw.y >> 16));
    int e0 = offs[i], e1 = offs[i + 1];
    float lac = 0.f;
    float a0 = 0.f, a1 = 0.f, a2 = 0.f, a3 = 0.f;
    int e = e0 + g;
    uint2 kA = {0, 0}, vA = {0, 0}, kB = {0, 0}, vB = {0, 0};
    if (e < e1) {
        const unsigned short* row = qkvs + (size_t)csr_src[e] * 512;
        kA = *(const uint2*)(row + 128 + d0);
        vA = *(const uint2*)(row + 256 + d0);
    }
    if (e + 2 < e1) {
        const unsigned short* row = qkvs + (size_t)csr_src[e + 2] * 512;
        kB = *(const uint2*)(row + 128 + d0);
        vB = *(const uint2*)(row + 256 + d0);
    }
    while (e < e1) {
        {   // edge e (buffer A); prefetch e+4 into A
            uint2 kk = kA, vv = vA;
            if (e + 4 < e1) {
                const unsigned short* row = qkvs + (size_t)csr_src[e + 4] * 512;
                kA = *(const uint2*)(row + 128 + d0);
                vA = *(const uint2*)(row + 256 + d0);
            }
            float k0 = bf2f((unsigned short)(kk.x & 0xffff)), k1 = bf2f((unsigned short)(kk.x >> 16));
            float k2 = bf2f((unsigned short)(kk.y & 0xffff)), k3 = bf2f((unsigned short)(kk.y >> 16));
            float p = q0 * k0 + q1 * k1 + q2 * k2 + q3 * k3;
            p += __shfl_xor(p, 1);
            p += __shfl_xor(p, 2);
            float w = __expf(p * 0.25f);
            float v0 = bf2f((unsigned short)(vv.x & 0xffff)), v1 = bf2f((unsigned short)(vv.x >> 16));
            float v2 = bf2f((unsigned short)(vv.y & 0xffff)), v3 = bf2f((unsigned short)(vv.y >> 16));
            a0 += w * v0; a1 += w * v1; a2 += w * v2; a3 += w * v3;
            lac += w;
        }
        if (e + 2 < e1) {  // edge e+2 (buffer B); prefetch e+6 into B
            uint2 kk = kB, vv = vB;
            if (e + 6 < e1) {
                const unsigned short* row = qkvs + (size_t)csr_src[e + 6] * 512;
                kB = *(const uint2*)(row + 128 + d0);
                vB = *(const uint2*)(row + 256 + d0);
            }
            float k0 = bf2f((unsigned short)(kk.x & 0xffff)), k1 = bf2f((unsigned short)(kk.x >> 16));
            float k2 = bf2f((unsigned short)(kk.y & 0xffff)), k3 = bf2f((unsigned short)(kk.y >> 16));
            float p = q0 * k0 + q1 * k1 + q2 * k2 + q3 * k3;
            p += __shfl_xor(p, 1);
            p += __shfl_xor(p, 2);
            float w = __expf(p * 0.25f);
            float v0 = bf2f((unsigned short)(vv.x & 0xffff)), v1 = bf2f((unsigned short)(vv.x >> 16));
            float v2 = bf2f((unsigned short)(vv.y & 0xffff)), v3 = bf2f((unsigned short)(vv.y >> 16));
            a0 += w * v0; a1 += w * v1; a2 += w * v2; a3 += w * v3;
            lac += w;
        }
        e += 4;
    }
    a0 += __shfl_xor(a0, 32);
    a1 += __shfl_xor(a1, 32);
    a2 += __shfl_xor(a2, 32);
    a3 += __shfl_xor(a3, 32);
    lac += __shfl_xor(lac, 32);
    float inv = 1.f / (lac + 1e-16f);
    float o0 = a0 * inv, o1 = a1 * inv, o2 = a2 * inv, o3 = a3 * inv;
    float r0 = bf2f((unsigned short)(rraw.x & 0xffff)), r1 = bf2f((unsigned short)(rraw.x >> 16));
    float r2 = bf2f((unsigned short)(rraw.y & 0xffff)), r3 = bf2f((unsigned short)(rraw.y >> 16));
    float part = o0 * Wb[d0] + o1 * Wb[d0 + 1] + o2 * Wb[d0 + 2] + o3 * Wb[d0 + 3]
               + r0 * Wb[128 + d0] + r1 * Wb[128 + d0 + 1]
               + r2 * Wb[128 + d0 + 2] + r3 * Wb[128 + d0 + 3]
               + (o0 - r0) * Wb[256 + d0] + (o1 - r1) * Wb[256 + d0 + 1]
               + (o2 - r2) * Wb[256 + d0 + 2] + (o3 - r3) * Wb[256 + d0 + 3];
    if (g) part = 0.f;
#pragma unroll
    for (int msk = 1; msk <= 32; msk <<= 1) part += __shfl_xor(part, msk);
    float gg = 1.f / (1.f + __expf(-part));
    if (g == 0) {
        float4 o4 = {gg * r0 + (1.f - gg) * o0, gg * r1 + (1.f - gg) * o1,
                     gg * r2 + (1.f - gg) * o2, gg * r3 + (1.f - gg) * o3};
        *(float4*)(out + (size_t)i * HIDDIM + d0) = o4;
    }
}

// ---------------- attention layer 3 (depth-2 pipelined edge loop) ----------------
// t node-major [N][1152] (t at 0, s at 1024). agg node-major [N][1024] bf16.
__global__ __launch_bounds__(64) void attn_big_kernel(
    const unsigned short* __restrict__ tbuf, const unsigned short* __restrict__ Acat,
    const int* __restrict__ offs, const int* __restrict__ csr_src,
    unsigned short* __restrict__ agg) {
    int i = blockIdx.x;
    int l = threadIdx.x;
    int doff = (l & 7) * 16;
    const unsigned short* tp = tbuf + (size_t)i * 1152 + l * 16;
    uint4 t0 = *(const uint4*)tp;
    uint4 t1 = *(const uint4*)(tp + 8);
    float tq[16];
    tq[0] = bf2f((unsigned short)(t0.x & 0xffff)); tq[1] = bf2f((unsigned short)(t0.x >> 16));
    tq[2] = bf2f((unsigned short)(t0.y & 0xffff)); tq[3] = bf2f((unsigned short)(t0.y >> 16));
    tq[4] = bf2f((unsigned short)(t0.z & 0xffff)); tq[5] = bf2f((unsigned short)(t0.z >> 16));
    tq[6] = bf2f((unsigned short)(t0.w & 0xffff)); tq[7] = bf2f((unsigned short)(t0.w >> 16));
    tq[8] = bf2f((unsigned short)(t1.x & 0xffff)); tq[9] = bf2f((unsigned short)(t1.x >> 16));
    tq[10] = bf2f((unsigned short)(t1.y & 0xffff)); tq[11] = bf2f((unsigned short)(t1.y >> 16));
    tq[12] = bf2f((unsigned short)(t1.z & 0xffff)); tq[13] = bf2f((unsigned short)(t1.z >> 16));
    tq[14] = bf2f((unsigned short)(t1.w & 0xffff)); tq[15] = bf2f((unsigned short)(t1.w >> 16));
    int e0 = offs[i], e1 = offs[i + 1];
    float ac[16];
#pragma unroll
    for (int j = 0; j < 16; ++j) ac[j] = 0.f;
    float lac = 0.f;
    int e = e0;
    uint4 kA0 = {0, 0, 0, 0}, kA1 = {0, 0, 0, 0};
    uint4 kB0 = {0, 0, 0, 0}, kB1 = {0, 0, 0, 0};
    if (e < e1) {
        const unsigned short* hp = Acat + (size_t)csr_src[e] * KC + doff;
        kA0 = *(const uint4*)hp;
        kA1 = *(const uint4*)(hp + 8);
    }
    if (e + 1 < e1) {
        const unsigned short* hp = Acat + (size_t)csr_src[e + 1] * KC + doff;
        kB0 = *(const uint4*)hp;
        kB1 = *(const uint4*)(hp + 8);
    }
    while (e < e1) {
        {   // edge e (buffer A); prefetch e+2 into A
            uint4 k0 = kA0, k1 = kA1;
            if (e + 2 < e1) {
                const unsigned short* hp = Acat + (size_t)csr_src[e + 2] * KC + doff;
                kA0 = *(const uint4*)hp;
                kA1 = *(const uint4*)(hp + 8);
            }
            float kk[16];
            kk[0] = bf2f((unsigned short)(k0.x & 0xffff)); kk[1] = bf2f((unsigned short)(k0.x >> 16));
            kk[2] = bf2f((unsigned short)(k0.y & 0xffff)); kk[3] = bf2f((unsigned short)(k0.y >> 16));
            kk[4] = bf2f((unsigned short)(k0.z & 0xffff)); kk[5] = bf2f((unsigned short)(k0.z >> 16));
            kk[6] = bf2f((unsigned short)(k0.w & 0xffff)); kk[7] = bf2f((unsigned short)(k0.w >> 16));
            kk[8] = bf2f((unsigned short)(k1.x & 0xffff)); kk[9] = bf2f((unsigned short)(k1.x >> 16));
            kk[10] = bf2f((unsigned short)(k1.y & 0xffff)); kk[11] = bf2f((unsigned short)(k1.y >> 16));
            kk[12] = bf2f((unsigned short)(k1.z & 0xffff)); kk[13] = bf2f((unsigned short)(k1.z >> 16));
            kk[14] = bf2f((unsigned short)(k1.w & 0xffff)); kk[15] = bf2f((unsigned short)(k1.w >> 16));
            float p = 0.f;
#pragma unroll
            for (int j = 0; j < 16; ++j) p = fmaf(tq[j], kk[j], p);
            p += __shfl_xor(p, 1);
            p += __shfl_xor(p, 2);
            p += __shfl_xor(p, 4);
            float w = __expf(p * 0.08838834764831845f);
#pragma unroll
            for (int j = 0; j < 16; ++j) ac[j] = fmaf(w, kk[j], ac[j]);
            lac += w;
        }
        if (e + 1 < e1) {  // edge e+1 (buffer B); prefetch e+3 into B
            uint4 k0 = kB0, k1 = kB1;
            if (e + 3 < e1) {
                const unsigned short* hp = Acat + (size_t)csr_src[e + 3] * KC + doff;
                kB0 = *(const uint4*)hp;
                kB1 = *(const uint4*)(hp + 8);
            }
            float kk[16];
            kk[0] = bf2f((unsigned short)(k0.x & 0xffff)); kk[1] = bf2f((unsigned short)(k0.x >> 16));
            kk[2] = bf2f((unsigned short)(k0.y & 0xffff)); kk[3] = bf2f((unsigned short)(k0.y >> 16));
            kk[4] = bf2f((unsigned short)(k0.z & 0xffff)); kk[5] = bf2f((unsigned short)(k0.z >> 16));
            kk[6] = bf2f((unsigned short)(k0.w & 0xffff)); kk[7] = bf2f((unsigned short)(k0.w >> 16));
            kk[8] = bf2f((unsigned short)(k1.x & 0xffff)); kk[9] = bf2f((unsigned short)(k1.x >> 16));
            kk[10] = bf2f((unsigned short)(k1.y & 0xffff)); kk[11] = bf2f((unsigned short)(k1.y >> 16));
            kk[12] = bf2f((unsigned short)(k1.z & 0xffff)); kk[13] = bf2f((unsigned short)(k1.z >> 16));
            kk[14] = bf2f((unsigned short)(k1.w & 0xffff)); kk[15] = bf2f((unsigned short)(k1.w >> 16));
            float p = 0.f;
#pragma unroll
            for (int j = 0; j < 16; ++j) p = fmaf(tq[j], kk[j], p);
            p += __shfl_xor(p, 1);
            p += __shfl_xor(p, 2);
            p += __shfl_xor(p, 4);
            float w = __expf(p * 0.08838834764831845f);
#pragma unroll
            for (int j = 0; j < 16; ++j) ac[j] = fmaf(w, kk[j], ac[j]);
            lac += w;
        }
        e += 2;
    }
    float inv = 1.f / (lac + 1e-16f);
    unsigned short* o = agg + (size_t)i * 1024 + l * 16;
    ushort4v o0 = {f2bf(ac[0] * inv), f2bf(ac[1] * inv), f2bf(ac[2] * inv), f2bf(ac[3] * inv)};
    ushort4v o1 = {f2bf(ac[4] * inv), f2bf(ac[5] * inv), f2bf(ac[6] * inv), f2bf(ac[7] * inv)};
    ushort4v o2 = {f2bf(ac[8] * inv), f2bf(ac[9] * inv), f2bf(ac[10] * inv), f2bf(ac[11] * inv)};
    ushort4v o3 = {f2bf(ac[12] * inv), f2bf(ac[13] * inv), f2bf(ac[14] * inv), f2bf(ac[15] * inv)};
    *(ushort4v*)o = o0;
    *(ushort4v*)(o + 4) = o1;
    *(ushort4v*)(o + 8) = o2;
    *(ushort4v*)(o + 12) = o3;
}

// ---------------- beta gate layer 3 + BN stats, fused (grid-stride) ----------------
// Also zeroes the 64x128 pool output (blocks 0..63).
__global__ __launch_bounds__(128) void beta3_stats_kernel(
    const float* __restrict__ omean, const unsigned short* __restrict__ tbuf,
    const float* __restrict__ Wb, float* __restrict__ out,
    float* __restrict__ stat, int n, float* __restrict__ pool_out) {
    int t = threadIdx.x;
    if (blockIdx.x < NGRAPH) pool_out[blockIdx.x * HIDDIM + t] = 0.f;
    __shared__ float wsum[2];
    float s = 0.f, sq = 0.f;
    for (int i = blockIdx.x; i < n; i += gridDim.x) {
        float o = omean[(size_t)i * HIDDIM + t];
        float r = bf2f(tbuf[(size_t)i * 1152 + 1024 + t]);
        float part = o * Wb[t] + r * Wb[128 + t] + (o - r) * Wb[256 + t];
#pragma unroll
        for (int msk = 1; msk <= 32; msk <<= 1) part += __shfl_xor(part, msk);
        if ((t & 63) == 0) wsum[t >> 6] = part;
        __syncthreads();
        float tot = wsum[0] + wsum[1];
        __syncthreads();
        float g = 1.f / (1.f + __expf(-tot));
        float v = g * r + (1.f - g) * o;
        out[(size_t)i * HIDDIM + t] = v;
        s += v;
        sq += v * v;
    }
    atomicAdd(&stat[t], s);
    atomicAdd(&stat[HIDDIM + t], sq);
}

// ---------------- batchnorm (layers 0-2) ----------------
__global__ __launch_bounds__(128) void bn_stats_kernel(const float* __restrict__ x,
                                                       float* __restrict__ stat, int n) {
    int t = threadIdx.x;
    float s = 0.f, sq = 0.f;
    for (int i = blockIdx.x; i < n; i += gridDim.x) {
        float v = x[(size_t)i * HIDDIM + t];
        s += v;
        sq += v * v;
    }
    atomicAdd(&stat[t], s);
    atomicAdd(&stat[HIDDIM + t], sq);
}

__global__ __launch_bounds__(128) void bn_apply_kernel(float* __restrict__ x,
                                                       const float* __restrict__ stat,
                                                       const float* __restrict__ gamma,
                                                       const float* __restrict__ beta, int n,
                                                       unsigned short* __restrict__ cat) {
    int t = threadIdx.x;
    float mu = stat[t] / (float)n;
    float var = stat[HIDDIM + t] / (float)n - mu * mu;
    float rs = rsqrtf(var + 1e-5f);
    float g = gamma[t], b = beta[t];
    for (int i = blockIdx.x; i < n; i += gridDim.x) {
        float v = x[(size_t)i * HIDDIM + t];
        v = fmaxf((v - mu) * rs * g + b, 0.f);
        x[(size_t)i * HIDDIM + t] = v;
        if (cat) {
            unsigned short hi = f2bf(v);
            unsigned short lo = f2bf(v - bf2f(hi));
            unsigned short* row = cat + (size_t)i * KC;
            row[t] = hi;
            row[128 + t] = lo;
            row[256 + t] = hi;
        }
    }
}

// ---------------- pool: fused BN+ReLU+mean, 16-way parallel partials ----------------
__global__ __launch_bounds__(256) void pool_bn_part_kernel(
    const float* __restrict__ x, const float* __restrict__ stat,
    const float* __restrict__ gamma, const float* __restrict__ beta,
    const int* __restrict__ gs, const int* __restrict__ ge,
    float* __restrict__ out, int n) {
    int g = blockIdx.x, c = blockIdx.y;
    int t = threadIdx.x;
    int f = t & 127, half = t >> 7;
    float mu = stat[f] / (float)n;
    float var = stat[HIDDIM + f] / (float)n - mu * mu;
    float rs = rsqrtf(var + 1e-5f);
    float ga = gamma[f], be = beta[f];
    int s = gs[g], e = ge[g];
    float acc = 0.f;
    for (int i = s + 2 * c + half; i < e; i += 16)
        acc += fmaxf((x[(size_t)i * HIDDIM + f] - mu) * rs * ga + be, 0.f);
    __shared__ float l0[128];
    if (half == 0) l0[f] = acc;
    __syncthreads();
    if (half == 1) {
        int cnt = e - s;
        float inv = 1.f / (float)(cnt > 0 ? cnt : 1);
        atomicAdd(&out[g * HIDDIM + f], (l0[f] + acc) * inv);
    }
}

// ---------------- host ----------------
extern "C" void kernel_launch(void* const* d_in, const int* in_sizes, int n_in,
                              void* d_out, int out_size, void* d_ws, size_t ws_size,
                              hipStream_t stream) {
    const float* x       = (const float*)d_in[0];
    const int*   ei      = (const int*)d_in[1];
    const int*   batch   = (const int*)d_in[2];
    const float* Wp      = (const float*)d_in[3];
    const float* bp      = (const float*)d_in[4];
    const float* Wq      = (const float*)d_in[5];
    const float* bq      = (const float*)d_in[6];
    const float* Wk      = (const float*)d_in[7];
    const float* bk      = (const float*)d_in[8];
    const float* Wv      = (const float*)d_in[9];
    const float* bv      = (const float*)d_in[10];
    const float* Ws      = (const float*)d_in[11];
    const float* bs      = (const float*)d_in[12];
    const float* Wbeta   = (const float*)d_in[13];
    const float* Wq3     = (const float*)d_in[14];
    const float* bq3     = (const float*)d_in[15];
    const float* Wk3     = (const float*)d_in[16];
    const float* bk3     = (const float*)d_in[17];
    const float* Wv3     = (const float*)d_in[18];
    const float* bv3     = (const float*)d_in[19];
    const float* Ws3     = (const float*)d_in[20];
    const float* bs3     = (const float*)d_in[21];
    const float* Wbeta3  = (const float*)d_in[22];
    const float* bn_gamma = (const float*)d_in[23];
    const float* bn_beta  = (const float*)d_in[24];
    float* out = (float*)d_out;
    (void)bk3;

    const int* esrc = ei;
    const int* edst = ei + NEDGES;

    char* wpc = (char*)d_ws;
    auto alloc = [&](size_t nbytes) -> char* {
        char* p = wpc;
        wpc += (nbytes + 255) & ~(size_t)255;
        return p;
    };
    unsigned short* Acat  = (unsigned short*)alloc((size_t)NPAD * KC * 2);      // 15.4 MB
    unsigned short* WtAll = (unsigned short*)alloc((size_t)2816 * KC * 2);      // 2.2 MB
    float* bcat   = (float*)alloc(2688 * 4);
    unsigned short* Wvm   = (unsigned short*)alloc((size_t)128 * 1024 * 2);     // 256 KB
    float* bvm    = (float*)alloc(128 * 4);
    unsigned short* tbuf  = (unsigned short*)alloc((size_t)NPAD * 1152 * 2);    // 46.3 MB (alias qkvs)
    unsigned short* aggb  = (unsigned short*)alloc((size_t)NPAD * 1024 * 2);    // 41 MB
    float* omean  = (float*)alloc((size_t)NNODES * HIDDIM * 4);                 // 10.2 MB
    float* hbuf   = (float*)alloc((size_t)NNODES * HIDDIM * 4);
    float* obuf   = (float*)alloc((size_t)NNODES * HIDDIM * 4);
    int*   deg    = (int*)alloc((2 * NNODES + 128 + 4 * 256) * 4);
    int*   cursor = deg + NNODES;
    int*   gs     = deg + 2 * NNODES;
    int*   ge     = gs + NGRAPH;
    float* bnstat4 = (float*)(deg + 2 * NNODES + 128);
    int*   chunk  = (int*)alloc(NNODES * 4);
    int*   bsum   = (int*)alloc(128 * 4);
    int*   offs   = (int*)alloc((NNODES + 1) * 4);
    int*   csrsrc = (int*)alloc(NEDGES * 4);

    unsigned short* WtQKVS = WtAll;                      // [3][512][KC] q|k|v|s
    unsigned short* Wpt    = WtAll + (size_t)1536 * KC;
    unsigned short* Wt3    = WtAll + (size_t)1664 * KC;  // [1152][KC] t|s3
    float* bQKVS = bcat;          // [3][512]
    float* b3    = bcat + 1536;   // [1152] t|s3
    unsigned short* qkvs = tbuf;  // layers 0-2 alias: [N][512]

    const int TB = 256;
    const int ZWORDS = 2 * NNODES + 128 + 4 * 256;
    zero_kernel<<<(ZWORDS + TB - 1) / TB, TB, 0, stream>>>((float*)deg, ZWORDS);
    count_deg_kernel<<<(NEDGES + TB - 1) / TB, TB, 0, stream>>>(edst, deg, NEDGES);
    const int NB = (NNODES + 255) / 256;
    scan1_kernel<<<NB, 256, 0, stream>>>(deg, chunk, bsum, NNODES);
    scan2_kernel<<<1, 128, 0, stream>>>(bsum, NB);
    scan3_kernel<<<NB, 256, 0, stream>>>(chunk, bsum, offs, NNODES);
    scatter_gb_kernel<<<(NEDGES + TB - 1) / TB, TB, 0, stream>>>(
        esrc, edst, offs, cursor, csrsrc, NEDGES, batch, gs, ge, NNODES);

    prep_all_kernel<<<3989, 128, 0, stream>>>(Wq, Wk, Wv, Ws, Wp, Ws3,
                                              bq, bk, bv, bs, bs3,
                                              Wq3, Wk3, bq3, Wv3, bv3,
                                              WtAll, bcat, Wvm, bvm);

    const int CATB = (NPAD * HIDDIM + TB - 1) / TB;
    const int GSW = 8 * ((GXTILES + 7) / 8);  // 160 swizzled x-slots

    cat_from_kernel<<<CATB, TB, 0, stream>>>(x, Acat);
    // initial projection, epilogue writes Acat format in place (BY=1: block
    // bx reads only its own 128 rows, writes only those rows — race-free)
    gemm_lds_kernel<unsigned short, 12, 1, KC, 2><<<GSW * 1, 256, 0, stream>>>(
        Acat, Wpt, bp, Acat, 0, NNODES);

    for (int li = 0; li < 3; ++li) {
        gemm_lds_kernel<unsigned short, 8, 4, KC, 1><<<GSW * 4, 256, 0, stream>>>(
            Acat, WtQKVS + (size_t)li * 512 * KC, bQKVS + li * 512, qkvs, 512, NNODES);
        attn_small_kernel<<<NNODES, 64, 0, stream>>>(qkvs, Wbeta + li * 384,
                                                     offs, csrsrc, obuf);
        float* st = bnstat4 + li * 256;
        bn_stats_kernel<<<640, 128, 0, stream>>>(obuf, st, NNODES);
        bn_apply_kernel<<<512, 128, 0, stream>>>(obuf, st, bn_gamma + li * HIDDIM,
                                                 bn_beta + li * HIDDIM, NNODES, Acat);
    }

    // ---- layer 3: t|s GEMM -> fused 8-head aggregate -> mean-V GEMM ->
    //      beta+stats (also zeroes pool out) -> 16-way pool with fused BN ----
    gemm_lds_kernel<unsigned short, 8, 9, KC, 1><<<GSW * 9, 256, 0, stream>>>(
        Acat, Wt3, b3, tbuf, 1152, NNODES);
    attn_big_kernel<<<NNODES, 64, 0, stream>>>(tbuf, Acat, offs, csrsrc, aggb);
    gemm_lds_kernel<float, 32, 1, 1024, 0><<<GSW, 256, 0, stream>>>(
        aggb, Wvm, bvm, omean, HIDDIM, NNODES);
    float* st3 = bnstat4 + 3 * 256;
    beta3_stats_kernel<<<512, 128, 0, stream>>>(omean, tbuf, Wbeta3, hbuf, st3, NNODES, out);
    pool_bn_part_kernel<<<dim3(NGRAPH, 8), 256, 0, stream>>>(
        hbuf, st3, bn_gamma + 3 * HIDDIM, bn_beta + 3 * HIDDIM, gs, ge, out, NNODES);
}

// Round 10
// 473.676 us; speedup vs baseline: 1.6408x; 1.0233x over previous
//
#include <hip/hip_runtime.h>
#include <math.h>

#define NNODES 20000
#define NPAD   20096   // 157 * 128
#define NEDGES 160000
#define HIDDIM 128
#define NHEADS 8
#define NGRAPH 64
#define KC 384   // concatenated K (hi | lo | hi)
#define GXTILES 157

typedef short short8 __attribute__((ext_vector_type(8)));
typedef float floatx4 __attribute__((ext_vector_type(4)));
typedef unsigned short ushort4v __attribute__((ext_vector_type(4)));

__device__ inline unsigned short f2bf(float x) {
    unsigned u = __float_as_uint(x);
    u += 0x7fff + ((u >> 16) & 1);
    return (unsigned short)(u >> 16);
}
__device__ inline float bf2f(unsigned short h) {
    return __uint_as_float(((unsigned)h) << 16);
}

// async global->LDS DMA, 16B per lane (HW: lds dst = uniform base + lane*16)
__device__ __forceinline__ void gload16(const unsigned short* g, unsigned short* l) {
    __builtin_amdgcn_global_load_lds(
        (const __attribute__((address_space(1))) unsigned int*)g,
        (__attribute__((address_space(3))) unsigned int*)l, 16, 0, 0);
}

// ---------------- utility ----------------
__global__ __launch_bounds__(256) void zero_kernel(float* __restrict__ p, int n) {
    int i = blockIdx.x * blockDim.x + threadIdx.x;
    if (i < n) p[i] = 0.f;
}

// ---------------- CSR build ----------------
__global__ __launch_bounds__(256) void count_deg_kernel(const int* __restrict__ dst,
                                                        int* __restrict__ deg, int e) {
    int i = blockIdx.x * blockDim.x + threadIdx.x;
    if (i < e) atomicAdd(&deg[dst[i]], 1);
}

__global__ __launch_bounds__(256) void scan1_kernel(const int* __restrict__ deg,
                                                    int* __restrict__ chunk,
                                                    int* __restrict__ bsum, int n) {
    __shared__ int buf[256];
    int t = threadIdx.x;
    int i = blockIdx.x * 256 + t;
    int v = (i < n) ? deg[i] : 0;
    buf[t] = v;
    __syncthreads();
    for (int off = 1; off < 256; off <<= 1) {
        int tmp = (t >= off) ? buf[t - off] : 0;
        __syncthreads();
        buf[t] += tmp;
        __syncthreads();
    }
    if (i < n) chunk[i] = buf[t];
    if (t == 255) bsum[blockIdx.x] = buf[255];
}

__global__ __launch_bounds__(128) void scan2_kernel(int* __restrict__ bsum, int nb) {
    __shared__ int buf[128];
    int t = threadIdx.x;
    int v = (t < nb) ? bsum[t] : 0;
    buf[t] = v;
    __syncthreads();
    for (int off = 1; off < 128; off <<= 1) {
        int tmp = (t >= off) ? buf[t - off] : 0;
        __syncthreads();
        buf[t] += tmp;
        __syncthreads();
    }
    if (t < nb) bsum[t] = buf[t] - v;
}

__global__ __launch_bounds__(256) void scan3_kernel(const int* __restrict__ chunk,
                                                    const int* __restrict__ bsum,
                                                    int* __restrict__ offs, int n) {
    int i = blockIdx.x * 256 + threadIdx.x;
    if (i < n) offs[i + 1] = chunk[i] + bsum[i >> 8];
    if (i == 0) offs[0] = 0;
}

// scatter (edges) + graph-boundary detection (nodes) fused: one dispatch
__global__ __launch_bounds__(256) void scatter_gb_kernel(
    const int* __restrict__ src, const int* __restrict__ dst,
    const int* __restrict__ offs, int* __restrict__ cursor,
    int* __restrict__ csr_src, int e,
    const int* __restrict__ batch, int* __restrict__ gs, int* __restrict__ ge, int n) {
    int i = blockIdx.x * blockDim.x + threadIdx.x;
    if (i < e) {
        int d = dst[i];
        int pos = offs[d] + atomicAdd(&cursor[d], 1);
        csr_src[pos] = src[i];
    }
    if (i < n) {
        int b = batch[i];
        if (i == 0 || batch[i - 1] != b) gs[b] = i;
        if (i == n - 1 || batch[i + 1] != b) ge[b] = i + 1;
    }
}

// ---------------- ALL weight prep in one dispatch ----------------
// Blocks [0,1536): layers 0-2 q|k|v|s rows; [1536,1664): Wp rows;
// [1664,2688): skip (t rows, filled below); [2688,2816): Ws3 rows;
// [2816,2837): bias entries; [2837,3861): mqk t rows; [3861,3989): Wvm rows.
__global__ __launch_bounds__(128) void prep_all_kernel(
    const float* __restrict__ Wq, const float* __restrict__ Wk,
    const float* __restrict__ Wv, const float* __restrict__ Ws,
    const float* __restrict__ Wp, const float* __restrict__ Ws3,
    const float* __restrict__ bq, const float* __restrict__ bk,
    const float* __restrict__ bv, const float* __restrict__ bs,
    const float* __restrict__ bs3,
    const float* __restrict__ Wq3, const float* __restrict__ Wk3,
    const float* __restrict__ bq3,
    const float* __restrict__ Wv3, const float* __restrict__ bv3,
    unsigned short* __restrict__ WtAll, float* __restrict__ bcat,
    unsigned short* __restrict__ Wvm, float* __restrict__ bvm) {
    int id = blockIdx.x;
    int k = threadIdx.x;
    if (id >= 3861) {  // Wvm rows
        int j = id - 3861;
#pragma unroll
        for (int h = 0; h < 8; ++h) {
            float w = Wv3[(size_t)k * 1024 + h * 128 + j] * 0.125f;
            Wvm[(size_t)j * 1024 + h * 128 + k] = f2bf(w);
        }
        if (k == 0) {
            float s = 0.f;
            for (int h = 0; h < 8; ++h) s += bv3[h * 128 + j];
            bvm[j] = s * 0.125f;
        }
        return;
    }
    if (id >= 2837) {  // mqk t rows: M_h = Wq_h Wk_h^T
        int hb = id - 2837;
        int h = hb >> 7, b = hb & 127;
        __shared__ float wk[128];
        wk[k] = Wk3[(size_t)b * 1024 + h * 128 + k];
        __syncthreads();
        const float* wq = Wq3 + (size_t)k * 1024 + h * 128;
        float acc = 0.f;
#pragma unroll 16
        for (int d = 0; d < 128; ++d) acc = fmaf(wq[d], wk[d], acc);
        unsigned short hi = f2bf(acc);
        unsigned short lo = f2bf(acc - bf2f(hi));
        unsigned short* dst = WtAll + (size_t)(1664 + h * 128 + b) * KC;
        dst[k] = hi;
        dst[128 + k] = hi;
        dst[256 + k] = lo;
        if (k == 0) {
            float bb = 0.f;
            for (int d = 0; d < 128; ++d) bb = fmaf(bq3[h * 128 + d], wk[d], bb);
            bcat[1536 + h * 128 + b] = bb;
        }
        return;
    }
    if (id >= 2816) {  // bias
        int idx = (id - 2816) * 128 + k;
        if (idx >= 2688) return;
        float v;
        if (idx < 1536) {
            int li = idx / 512, n = idx % 512, sel = n >> 7, np = n & 127;
            const float* b = (sel == 0) ? bq : (sel == 1) ? bk : (sel == 2) ? bv : bs;
            v = b[li * 128 + np];
        } else if (idx < 2560) {
            return;  // t bias filled above
        } else {
            v = bs3[idx - 2560];
        }
        bcat[idx] = v;
        return;
    }
    float w;
    if (id < 1536) {
        int li = id / 512, n = id % 512, sel = n >> 7, np = n & 127;
        const float* W = (sel == 0) ? Wq : (sel == 1) ? Wk : (sel == 2) ? Wv : Ws;
        w = W[li * 16384 + k * 128 + np];
    } else if (id < 1664) {
        w = Wp[k * 128 + (id - 1536)];
    } else if (id < 2688) {
        return;  // t rows handled by mqk branch
    } else {
        w = Ws3[k * 128 + (id - 2688)];
    }
    unsigned short hi = f2bf(w);
    unsigned short lo = f2bf(w - bf2f(hi));
    unsigned short* dst = WtAll + (size_t)id * KC;
    dst[k] = hi;
    dst[128 + k] = hi;
    dst[256 + k] = lo;
}

// ---------------- activation -> split-bf16 A_cat ----------------
// Full hi|lo|hi: the Wp GEMM consumes all three segments (KG=12).
__global__ __launch_bounds__(256) void cat_from_kernel(const float* __restrict__ h,
                                                       unsigned short* __restrict__ Acat) {
    int idx = blockIdx.x * 256 + threadIdx.x;
    if (idx >= NPAD * HIDDIM) return;
    int r = idx >> 7, k = idx & 127;
    float x = (r < NNODES) ? h[idx] : 0.f;
    unsigned short hi = f2bf(x);
    unsigned short lo = f2bf(x - bf2f(hi));
    unsigned short* row = Acat + (size_t)r * KC;
    row[k] = hi;
    row[128 + k] = lo;
    row[256 + k] = hi;
}

// ---------------- LDS-staged MFMA GEMM (XCD swizzle, global_load_lds) ----------------
// Tile: 128 nodes x 128 feats per block, 4 waves. BK=32 double-buffered LDS
// (32KB), staging via global_load_lds width 16. Chunk-XOR swizzle on BOTH
// the pre-swizzled global source and the ds_read address (rule 21).
// OMODE: 0 = f32 out (stride M), 1 = bf16 out (stride M),
//        2 = Acat hi|lo out (stride KC; in-place safe for BY=1). Third
//            segment NOT written: downstream readers of this output are
//            qkvs GEMM (KG=8, k<256) and attn_big (doff<128) only.
template <typename OutT, int KG, int BY, int ST, int OMODE>
__global__ __launch_bounds__(256) void gemm_lds_kernel(
    const unsigned short* __restrict__ A, const unsigned short* __restrict__ Wt,
    const float* __restrict__ bias, OutT* __restrict__ C, int M, int nrows) {
    int id = blockIdx.x;
    int xcd = id & 7;
    int idx = id >> 3;
    int bx = (idx / BY) * 8 + xcd;
    int by = idx % BY;
    if (bx >= GXTILES) return;

    __shared__ unsigned short lds[2][2][4096];  // [buf][A/W][128 rows * 32 shorts]

    int tid = threadIdx.x;
    int lane = tid & 63;
    int wave = tid >> 6;
    int m = lane & 15;
    int q = lane >> 4;
    int nodeBase = bx * 128 + (wave & 1) * 64;
    int featBase = by * 128 + (wave >> 1) * 64;

    const unsigned short* gA = A + (size_t)bx * 128 * ST;
    const unsigned short* gW = Wt + (size_t)by * 128 * ST;

    int rs = lane >> 2;
    int cp0 = lane & 3;

    auto stagef = [&](int buf, int kk) {
        int kof = kk * 32;
#pragma unroll
        for (int jj = 0; jj < 2; ++jj) {
            int j = wave * 2 + jj;
            int row = j * 16 + rs;
            int g = cp0 ^ ((row >> 1) & 3);
            gload16(gA + (size_t)row * ST + kof + g * 8,
                    &lds[buf][0][0] + (size_t)j * 512);
            gload16(gW + (size_t)row * ST + kof + g * 8,
                    &lds[buf][1][0] + (size_t)j * 512);
        }
    };

    floatx4 acc[4][4];
#pragma unroll
    for (int r = 0; r < 4; ++r)
#pragma unroll
        for (int c = 0; c < 4; ++c) acc[r][c] = (floatx4){0.f, 0.f, 0.f, 0.f};

    stagef(0, 0);
    __syncthreads();

    for (int kg = 0; kg < KG; ++kg) {
        int cur = kg & 1;
        if (kg + 1 < KG) stagef(cur ^ 1, kg + 1);
        short8 a[4], b[4];
#pragma unroll
        for (int r = 0; r < 4; ++r) {
            int wr = (wave >> 1) * 64 + r * 16 + m;
            int cp = q ^ ((wr >> 1) & 3);
            a[r] = *(const short8*)(&lds[cur][1][0] + wr * 32 + cp * 8);
        }
#pragma unroll
        for (int c = 0; c < 4; ++c) {
            int ar = (wave & 1) * 64 + c * 16 + m;
            int cp = q ^ ((ar >> 1) & 3);
            b[c] = *(const short8*)(&lds[cur][0][0] + ar * 32 + cp * 8);
        }
#pragma unroll
        for (int r = 0; r < 4; ++r)
#pragma unroll
            for (int c = 0; c < 4; ++c)
                acc[r][c] = __builtin_amdgcn_mfma_f32_16x16x32_bf16(a[r], b[c], acc[r][c], 0, 0, 0);
        __syncthreads();
    }

    float4 bv[4];
#pragma unroll
    for (int r = 0; r < 4; ++r) bv[r] = *(const float4*)(bias + featBase + r * 16 + q * 4);
#pragma unroll
    for (int c = 0; c < 4; ++c) {
        int node = nodeBase + c * 16 + m;
        if (node < nrows) {
#pragma unroll
            for (int r = 0; r < 4; ++r) {
                int f0 = featBase + r * 16 + q * 4;
                float v0 = acc[r][c][0] + bv[r].x;
                float v1 = acc[r][c][1] + bv[r].y;
                float v2 = acc[r][c][2] + bv[r].z;
                float v3 = acc[r][c][3] + bv[r].w;
                if (OMODE == 2) {
                    unsigned short* row = (unsigned short*)C + (size_t)node * KC;
                    unsigned short h0 = f2bf(v0), h1 = f2bf(v1), h2 = f2bf(v2), h3 = f2bf(v3);
                    ushort4v hiv = {h0, h1, h2, h3};
                    ushort4v lov = {f2bf(v0 - bf2f(h0)), f2bf(v1 - bf2f(h1)),
                                    f2bf(v2 - bf2f(h2)), f2bf(v3 - bf2f(h3))};
                    *(ushort4v*)(row + f0) = hiv;
                    *(ushort4v*)(row + 128 + f0) = lov;
                    // third segment (row+256) intentionally not written (dead)
                } else if (OMODE == 1) {
                    ushort4v o = {f2bf(v0), f2bf(v1), f2bf(v2), f2bf(v3)};
                    *(ushort4v*)((unsigned short*)C + (size_t)node * M + f0) = o;
                } else {
                    float4 o = {v0, v1, v2, v3};
                    *(float4*)((float*)C + (size_t)node * M + f0) = o;
                }
            }
        }
    }
}

// ---------------- attention layers 0-2 (depth-2 pipelined edge loop) ----------------
__global__ __launch_bounds__(64) void attn_small_kernel(
    const unsigned short* __restrict__ qkvs,
    const float* __restrict__ Wb,
    const int* __restrict__ offs, const int* __restrict__ csr_src,
    float* __restrict__ out) {
    int i = blockIdx.x;
    int l = threadIdx.x;
    int g = l >> 5;
    int d0 = (l & 31) * 4;
    uint2 qraw = *(const uint2*)(qkvs + (size_t)i * 512 + d0);
    uint2 rraw = *(const uint2*)(qkvs + (size_t)i * 512 + 384 + d0);
    float q0 = bf2f((unsigned short)(qraw.x & 0xffff)), q1 = bf2f((unsigned short)(qraw.x >> 16));
    float q2 = bf2f((unsigned short)(qraw.y & 0xffff)), q3 = bf2f((unsigned short)(qraw.y >> 16));
    int e0 = offs[i], e1 = offs[i + 1];
    float lac = 0.f;
    float a0 = 0.f, a1 = 0.f, a2 = 0.f, a3 = 0.f;
    int e = e0 + g;
    uint2 kA = {0, 0}, vA = {0, 0}, kB = {0, 0}, vB = {0, 0};
    if (e < e1) {
        const unsigned short* row = qkvs + (size_t)csr_src[e] * 512;
        kA = *(const uint2*)(row + 128 + d0);
        vA = *(const uint2*)(row + 256 + d0);
    }
    if (e + 2 < e1) {
        const unsigned short* row = qkvs + (size_t)csr_src[e + 2] * 512;
        kB = *(const uint2*)(row + 128 + d0);
        vB = *(const uint2*)(row + 256 + d0);
    }
    while (e < e1) {
        {   // edge e (buffer A); prefetch e+4 into A
            uint2 kk = kA, vv = vA;
            if (e + 4 < e1) {
                const unsigned short* row = qkvs + (size_t)csr_src[e + 4] * 512;
                kA = *(const uint2*)(row + 128 + d0);
                vA = *(const uint2*)(row + 256 + d0);
            }
            float k0 = bf2f((unsigned short)(kk.x & 0xffff)), k1 = bf2f((unsigned short)(kk.x >> 16));
            float k2 = bf2f((unsigned short)(kk.y & 0xffff)), k3 = bf2f((unsigned short)(kk.y >> 16));
            float p = q0 * k0 + q1 * k1 + q2 * k2 + q3 * k3;
            p += __shfl_xor(p, 1);
            p += __shfl_xor(p, 2);
            float w = __expf(p * 0.25f);
            float v0 = bf2f((unsigned short)(vv.x & 0xffff)), v1 = bf2f((unsigned short)(vv.x >> 16));
            float v2 = bf2f((unsigned short)(vv.y & 0xffff)), v3 = bf2f((unsigned short)(vv.y >> 16));
            a0 += w * v0; a1 += w * v1; a2 += w * v2; a3 += w * v3;
            lac += w;
        }
        if (e + 2 < e1) {  // edge e+2 (buffer B); prefetch e+6 into B
            uint2 kk = kB, vv = vB;
            if (e + 6 < e1) {
                const unsigned short* row = qkvs + (size_t)csr_src[e + 6] * 512;
                kB = *(const uint2*)(row + 128 + d0);
                vB = *(const uint2*)(row + 256 + d0);
            }
            float k0 = bf2f((unsigned short)(kk.x & 0xffff)), k1 = bf2f((unsigned short)(kk.x >> 16));
            float k2 = bf2f((unsigned short)(kk.y & 0xffff)), k3 = bf2f((unsigned short)(kk.y >> 16));
            float p = q0 * k0 + q1 * k1 + q2 * k2 + q3 * k3;
            p += __shfl_xor(p, 1);
            p += __shfl_xor(p, 2);
            float w = __expf(p * 0.25f);
            float v0 = bf2f((unsigned short)(vv.x & 0xffff)), v1 = bf2f((unsigned short)(vv.x >> 16));
            float v2 = bf2f((unsigned short)(vv.y & 0xffff)), v3 = bf2f((unsigned short)(vv.y >> 16));
            a0 += w * v0; a1 += w * v1; a2 += w * v2; a3 += w * v3;
            lac += w;
        }
        e += 4;
    }
    a0 += __shfl_xor(a0, 32);
    a1 += __shfl_xor(a1, 32);
    a2 += __shfl_xor(a2, 32);
    a3 += __shfl_xor(a3, 32);
    lac += __shfl_xor(lac, 32);
    float inv = 1.f / (lac + 1e-16f);
    float o0 = a0 * inv, o1 = a1 * inv, o2 = a2 * inv, o3 = a3 * inv;
    float r0 = bf2f((unsigned short)(rraw.x & 0xffff)), r1 = bf2f((unsigned short)(rraw.x >> 16));
    float r2 = bf2f((unsigned short)(rraw.y & 0xffff)), r3 = bf2f((unsigned short)(rraw.y >> 16));
    float part = o0 * Wb[d0] + o1 * Wb[d0 + 1] + o2 * Wb[d0 + 2] + o3 * Wb[d0 + 3]
               + r0 * Wb[128 + d0] + r1 * Wb[128 + d0 + 1]
               + r2 * Wb[128 + d0 + 2] + r3 * Wb[128 + d0 + 3]
               + (o0 - r0) * Wb[256 + d0] + (o1 - r1) * Wb[256 + d0 + 1]
               + (o2 - r2) * Wb[256 + d0 + 2] + (o3 - r3) * Wb[256 + d0 + 3];
    if (g) part = 0.f;
#pragma unroll
    for (int msk = 1; msk <= 32; msk <<= 1) part += __shfl_xor(part, msk);
    float gg = 1.f / (1.f + __expf(-part));
    if (g == 0) {
        float4 o4 = {gg * r0 + (1.f - gg) * o0, gg * r1 + (1.f - gg) * o1,
                     gg * r2 + (1.f - gg) * o2, gg * r3 + (1.f - gg) * o3};
        *(float4*)(out + (size_t)i * HIDDIM + d0) = o4;
    }
}

// ---------------- attention layer 3 (depth-2 pipelined edge loop) ----------------
// t node-major [N][1152] (t at 0, s at 1024). agg node-major [N][1024] bf16.
__global__ __launch_bounds__(64) void attn_big_kernel(
    const unsigned short* __restrict__ tbuf, const unsigned short* __restrict__ Acat,
    const int* __restrict__ offs, const int* __restrict__ csr_src,
    unsigned short* __restrict__ agg) {
    int i = blockIdx.x;
    int l = threadIdx.x;
    int doff = (l & 7) * 16;
    const unsigned short* tp = tbuf + (size_t)i * 1152 + l * 16;
    uint4 t0 = *(const uint4*)tp;
    uint4 t1 = *(const uint4*)(tp + 8);
    float tq[16];
    tq[0] = bf2f((unsigned short)(t0.x & 0xffff)); tq[1] = bf2f((unsigned short)(t0.x >> 16));
    tq[2] = bf2f((unsigned short)(t0.y & 0xffff)); tq[3] = bf2f((unsigned short)(t0.y >> 16));
    tq[4] = bf2f((unsigned short)(t0.z & 0xffff)); tq[5] = bf2f((unsigned short)(t0.z >> 16));
    tq[6] = bf2f((unsigned short)(t0.w & 0xffff)); tq[7] = bf2f((unsigned short)(t0.w >> 16));
    tq[8] = bf2f((unsigned short)(t1.x & 0xffff)); tq[9] = bf2f((unsigned short)(t1.x >> 16));
    tq[10] = bf2f((unsigned short)(t1.y & 0xffff)); tq[11] = bf2f((unsigned short)(t1.y >> 16));
    tq[12] = bf2f((unsigned short)(t1.z & 0xffff)); tq[13] = bf2f((unsigned short)(t1.z >> 16));
    tq[14] = bf2f((unsigned short)(t1.w & 0xffff)); tq[15] = bf2f((unsigned short)(t1.w >> 16));
    int e0 = offs[i], e1 = offs[i + 1];
    float ac[16];
#pragma unroll
    for (int j = 0; j < 16; ++j) ac[j] = 0.f;
    float lac = 0.f;
    int e = e0;
    uint4 kA0 = {0, 0, 0, 0}, kA1 = {0, 0, 0, 0};
    uint4 kB0 = {0, 0, 0, 0}, kB1 = {0, 0, 0, 0};
    if (e < e1) {
        const unsigned short* hp = Acat + (size_t)csr_src[e] * KC + doff;
        kA0 = *(const uint4*)hp;
        kA1 = *(const uint4*)(hp + 8);
    }
    if (e + 1 < e1) {
        const unsigned short* hp = Acat + (size_t)csr_src[e + 1] * KC + doff;
        kB0 = *(const uint4*)hp;
        kB1 = *(const uint4*)(hp + 8);
    }
    while (e < e1) {
        {   // edge e (buffer A); prefetch e+2 into A
            uint4 k0 = kA0, k1 = kA1;
            if (e + 2 < e1) {
                const unsigned short* hp = Acat + (size_t)csr_src[e + 2] * KC + doff;
                kA0 = *(const uint4*)hp;
                kA1 = *(const uint4*)(hp + 8);
            }
            float kk[16];
            kk[0] = bf2f((unsigned short)(k0.x & 0xffff)); kk[1] = bf2f((unsigned short)(k0.x >> 16));
            kk[2] = bf2f((unsigned short)(k0.y & 0xffff)); kk[3] = bf2f((unsigned short)(k0.y >> 16));
            kk[4] = bf2f((unsigned short)(k0.z & 0xffff)); kk[5] = bf2f((unsigned short)(k0.z >> 16));
            kk[6] = bf2f((unsigned short)(k0.w & 0xffff)); kk[7] = bf2f((unsigned short)(k0.w >> 16));
            kk[8] = bf2f((unsigned short)(k1.x & 0xffff)); kk[9] = bf2f((unsigned short)(k1.x >> 16));
            kk[10] = bf2f((unsigned short)(k1.y & 0xffff)); kk[11] = bf2f((unsigned short)(k1.y >> 16));
            kk[12] = bf2f((unsigned short)(k1.z & 0xffff)); kk[13] = bf2f((unsigned short)(k1.z >> 16));
            kk[14] = bf2f((unsigned short)(k1.w & 0xffff)); kk[15] = bf2f((unsigned short)(k1.w >> 16));
            float p = 0.f;
#pragma unroll
            for (int j = 0; j < 16; ++j) p = fmaf(tq[j], kk[j], p);
            p += __shfl_xor(p, 1);
            p += __shfl_xor(p, 2);
            p += __shfl_xor(p, 4);
            float w = __expf(p * 0.08838834764831845f);
#pragma unroll
            for (int j = 0; j < 16; ++j) ac[j] = fmaf(w, kk[j], ac[j]);
            lac += w;
        }
        if (e + 1 < e1) {  // edge e+1 (buffer B); prefetch e+3 into B
            uint4 k0 = kB0, k1 = kB1;
            if (e + 3 < e1) {
                const unsigned short* hp = Acat + (size_t)csr_src[e + 3] * KC + doff;
                kB0 = *(const uint4*)hp;
                kB1 = *(const uint4*)(hp + 8);
            }
            float kk[16];
            kk[0] = bf2f((unsigned short)(k0.x & 0xffff)); kk[1] = bf2f((unsigned short)(k0.x >> 16));
            kk[2] = bf2f((unsigned short)(k0.y & 0xffff)); kk[3] = bf2f((unsigned short)(k0.y >> 16));
            kk[4] = bf2f((unsigned short)(k0.z & 0xffff)); kk[5] = bf2f((unsigned short)(k0.z >> 16));
            kk[6] = bf2f((unsigned short)(k0.w & 0xffff)); kk[7] = bf2f((unsigned short)(k0.w >> 16));
            kk[8] = bf2f((unsigned short)(k1.x & 0xffff)); kk[9] = bf2f((unsigned short)(k1.x >> 16));
            kk[10] = bf2f((unsigned short)(k1.y & 0xffff)); kk[11] = bf2f((unsigned short)(k1.y >> 16));
            kk[12] = bf2f((unsigned short)(k1.z & 0xffff)); kk[13] = bf2f((unsigned short)(k1.z >> 16));
            kk[14] = bf2f((unsigned short)(k1.w & 0xffff)); kk[15] = bf2f((unsigned short)(k1.w >> 16));
            float p = 0.f;
#pragma unroll
            for (int j = 0; j < 16; ++j) p = fmaf(tq[j], kk[j], p);
            p += __shfl_xor(p, 1);
            p += __shfl_xor(p, 2);
            p += __shfl_xor(p, 4);
            float w = __expf(p * 0.08838834764831845f);
#pragma unroll
            for (int j = 0; j < 16; ++j) ac[j] = fmaf(w, kk[j], ac[j]);
            lac += w;
        }
        e += 2;
    }
    float inv = 1.f / (lac + 1e-16f);
    unsigned short* o = agg + (size_t)i * 1024 + l * 16;
    ushort4v o0 = {f2bf(ac[0] * inv), f2bf(ac[1] * inv), f2bf(ac[2] * inv), f2bf(ac[3] * inv)};
    ushort4v o1 = {f2bf(ac[4] * inv), f2bf(ac[5] * inv), f2bf(ac[6] * inv), f2bf(ac[7] * inv)};
    ushort4v o2 = {f2bf(ac[8] * inv), f2bf(ac[9] * inv), f2bf(ac[10] * inv), f2bf(ac[11] * inv)};
    ushort4v o3 = {f2bf(ac[12] * inv), f2bf(ac[13] * inv), f2bf(ac[14] * inv), f2bf(ac[15] * inv)};
    *(ushort4v*)o = o0;
    *(ushort4v*)(o + 4) = o1;
    *(ushort4v*)(o + 8) = o2;
    *(ushort4v*)(o + 12) = o3;
}

// ---------------- beta gate layer 3 + BN stats, fused (grid-stride) ----------------
// Also zeroes the 64x128 pool output (blocks 0..63).
__global__ __launch_bounds__(128) void beta3_stats_kernel(
    const float* __restrict__ omean, const unsigned short* __restrict__ tbuf,
    const float* __restrict__ Wb, float* __restrict__ out,
    float* __restrict__ stat, int n, float* __restrict__ pool_out) {
    int t = threadIdx.x;
    if (blockIdx.x < NGRAPH) pool_out[blockIdx.x * HIDDIM + t] = 0.f;
    __shared__ float wsum[2];
    float s = 0.f, sq = 0.f;
    for (int i = blockIdx.x; i < n; i += gridDim.x) {
        float o = omean[(size_t)i * HIDDIM + t];
        float r = bf2f(tbuf[(size_t)i * 1152 + 1024 + t]);
        float part = o * Wb[t] + r * Wb[128 + t] + (o - r) * Wb[256 + t];
#pragma unroll
        for (int msk = 1; msk <= 32; msk <<= 1) part += __shfl_xor(part, msk);
        if ((t & 63) == 0) wsum[t >> 6] = part;
        __syncthreads();
        float tot = wsum[0] + wsum[1];
        __syncthreads();
        float g = 1.f / (1.f + __expf(-tot));
        float v = g * r + (1.f - g) * o;
        out[(size_t)i * HIDDIM + t] = v;
        s += v;
        sq += v * v;
    }
    atomicAdd(&stat[t], s);
    atomicAdd(&stat[HIDDIM + t], sq);
}

// ---------------- batchnorm (layers 0-2) ----------------
__global__ __launch_bounds__(128) void bn_stats_kernel(const float* __restrict__ x,
                                                       float* __restrict__ stat, int n) {
    int t = threadIdx.x;
    float s = 0.f, sq = 0.f;
    for (int i = blockIdx.x; i < n; i += gridDim.x) {
        float v = x[(size_t)i * HIDDIM + t];
        s += v;
        sq += v * v;
    }
    atomicAdd(&stat[t], s);
    atomicAdd(&stat[HIDDIM + t], sq);
}

// Writes ONLY the Acat hi|lo segments: the x writeback is dead (obuf is
// fully overwritten by the next layer's attn_small), and the third Acat
// segment is unread by KG=8 GEMMs / attn_big (doff<128).
__global__ __launch_bounds__(128) void bn_apply_kernel(const float* __restrict__ x,
                                                       const float* __restrict__ stat,
                                                       const float* __restrict__ gamma,
                                                       const float* __restrict__ beta, int n,
                                                       unsigned short* __restrict__ cat) {
    int t = threadIdx.x;
    float mu = stat[t] / (float)n;
    float var = stat[HIDDIM + t] / (float)n - mu * mu;
    float rs = rsqrtf(var + 1e-5f);
    float g = gamma[t], b = beta[t];
    for (int i = blockIdx.x; i < n; i += gridDim.x) {
        float v = x[(size_t)i * HIDDIM + t];
        v = fmaxf((v - mu) * rs * g + b, 0.f);
        unsigned short hi = f2bf(v);
        unsigned short lo = f2bf(v - bf2f(hi));
        unsigned short* row = cat + (size_t)i * KC;
        row[t] = hi;
        row[128 + t] = lo;
    }
}

// ---------------- pool: fused BN+ReLU+mean, 16-way parallel partials ----------------
__global__ __launch_bounds__(256) void pool_bn_part_kernel(
    const float* __restrict__ x, const float* __restrict__ stat,
    const float* __restrict__ gamma, const float* __restrict__ beta,
    const int* __restrict__ gs, const int* __restrict__ ge,
    float* __restrict__ out, int n) {
    int g = blockIdx.x, c = blockIdx.y;
    int t = threadIdx.x;
    int f = t & 127, half = t >> 7;
    float mu = stat[f] / (float)n;
    float var = stat[HIDDIM + f] / (float)n - mu * mu;
    float rs = rsqrtf(var + 1e-5f);
    float ga = gamma[f], be = beta[f];
    int s = gs[g], e = ge[g];
    float acc = 0.f;
    for (int i = s + 2 * c + half; i < e; i += 16)
        acc += fmaxf((x[(size_t)i * HIDDIM + f] - mu) * rs * ga + be, 0.f);
    __shared__ float l0[128];
    if (half == 0) l0[f] = acc;
    __syncthreads();
    if (half == 1) {
        int cnt = e - s;
        float inv = 1.f / (float)(cnt > 0 ? cnt : 1);
        atomicAdd(&out[g * HIDDIM + f], (l0[f] + acc) * inv);
    }
}

// ---------------- host ----------------
extern "C" void kernel_launch(void* const* d_in, const int* in_sizes, int n_in,
                              void* d_out, int out_size, void* d_ws, size_t ws_size,
                              hipStream_t stream) {
    const float* x       = (const float*)d_in[0];
    const int*   ei      = (const int*)d_in[1];
    const int*   batch   = (const int*)d_in[2];
    const float* Wp      = (const float*)d_in[3];
    const float* bp      = (const float*)d_in[4];
    const float* Wq      = (const float*)d_in[5];
    const float* bq      = (const float*)d_in[6];
    const float* Wk      = (const float*)d_in[7];
    const float* bk      = (const float*)d_in[8];
    const float* Wv      = (const float*)d_in[9];
    const float* bv      = (const float*)d_in[10];
    const float* Ws      = (const float*)d_in[11];
    const float* bs      = (const float*)d_in[12];
    const float* Wbeta   = (const float*)d_in[13];
    const float* Wq3     = (const float*)d_in[14];
    const float* bq3     = (const float*)d_in[15];
    const float* Wk3     = (const float*)d_in[16];
    const float* bk3     = (const float*)d_in[17];
    const float* Wv3     = (const float*)d_in[18];
    const float* bv3     = (const float*)d_in[19];
    const float* Ws3     = (const float*)d_in[20];
    const float* bs3     = (const float*)d_in[21];
    const float* Wbeta3  = (const float*)d_in[22];
    const float* bn_gamma = (const float*)d_in[23];
    const float* bn_beta  = (const float*)d_in[24];
    float* out = (float*)d_out;
    (void)bk3;

    const int* esrc = ei;
    const int* edst = ei + NEDGES;

    char* wpc = (char*)d_ws;
    auto alloc = [&](size_t nbytes) -> char* {
        char* p = wpc;
        wpc += (nbytes + 255) & ~(size_t)255;
        return p;
    };
    unsigned short* Acat  = (unsigned short*)alloc((size_t)NPAD * KC * 2);      // 15.4 MB
    unsigned short* WtAll = (unsigned short*)alloc((size_t)2816 * KC * 2);      // 2.2 MB
    float* bcat   = (float*)alloc(2688 * 4);
    unsigned short* Wvm   = (unsigned short*)alloc((size_t)128 * 1024 * 2);     // 256 KB
    float* bvm    = (float*)alloc(128 * 4);
    unsigned short* tbuf  = (unsigned short*)alloc((size_t)NPAD * 1152 * 2);    // 46.3 MB (alias qkvs)
    unsigned short* aggb  = (unsigned short*)alloc((size_t)NPAD * 1024 * 2);    // 41 MB
    float* omean  = (float*)alloc((size_t)NNODES * HIDDIM * 4);                 // 10.2 MB
    float* hbuf   = (float*)alloc((size_t)NNODES * HIDDIM * 4);
    float* obuf   = (float*)alloc((size_t)NNODES * HIDDIM * 4);
    int*   deg    = (int*)alloc((2 * NNODES + 128 + 4 * 256) * 4);
    int*   cursor = deg + NNODES;
    int*   gs     = deg + 2 * NNODES;
    int*   ge     = gs + NGRAPH;
    float* bnstat4 = (float*)(deg + 2 * NNODES + 128);
    int*   chunk  = (int*)alloc(NNODES * 4);
    int*   bsum   = (int*)alloc(128 * 4);
    int*   offs   = (int*)alloc((NNODES + 1) * 4);
    int*   csrsrc = (int*)alloc(NEDGES * 4);

    unsigned short* WtQKVS = WtAll;                      // [3][512][KC] q|k|v|s
    unsigned short* Wpt    = WtAll + (size_t)1536 * KC;
    unsigned short* Wt3    = WtAll + (size_t)1664 * KC;  // [1152][KC] t|s3
    float* bQKVS = bcat;          // [3][512]
    float* b3    = bcat + 1536;   // [1152] t|s3
    unsigned short* qkvs = tbuf;  // layers 0-2 alias: [N][512]

    const int TB = 256;
    const int ZWORDS = 2 * NNODES + 128 + 4 * 256;
    zero_kernel<<<(ZWORDS + TB - 1) / TB, TB, 0, stream>>>((float*)deg, ZWORDS);
    count_deg_kernel<<<(NEDGES + TB - 1) / TB, TB, 0, stream>>>(edst, deg, NEDGES);
    const int NB = (NNODES + 255) / 256;
    scan1_kernel<<<NB, 256, 0, stream>>>(deg, chunk, bsum, NNODES);
    scan2_kernel<<<1, 128, 0, stream>>>(bsum, NB);
    scan3_kernel<<<NB, 256, 0, stream>>>(chunk, bsum, offs, NNODES);
    scatter_gb_kernel<<<(NEDGES + TB - 1) / TB, TB, 0, stream>>>(
        esrc, edst, offs, cursor, csrsrc, NEDGES, batch, gs, ge, NNODES);

    prep_all_kernel<<<3989, 128, 0, stream>>>(Wq, Wk, Wv, Ws, Wp, Ws3,
                                              bq, bk, bv, bs, bs3,
                                              Wq3, Wk3, bq3, Wv3, bv3,
                                              WtAll, bcat, Wvm, bvm);

    const int CATB = (NPAD * HIDDIM + TB - 1) / TB;
    const int GSW = 8 * ((GXTILES + 7) / 8);  // 160 swizzled x-slots

    cat_from_kernel<<<CATB, TB, 0, stream>>>(x, Acat);
    // initial projection, epilogue writes Acat format in place (BY=1: block
    // bx reads only its own 128 rows, writes only those rows — race-free)
    gemm_lds_kernel<unsigned short, 12, 1, KC, 2><<<GSW * 1, 256, 0, stream>>>(
        Acat, Wpt, bp, Acat, 0, NNODES);

    for (int li = 0; li < 3; ++li) {
        gemm_lds_kernel<unsigned short, 8, 4, KC, 1><<<GSW * 4, 256, 0, stream>>>(
            Acat, WtQKVS + (size_t)li * 512 * KC, bQKVS + li * 512, qkvs, 512, NNODES);
        attn_small_kernel<<<NNODES, 64, 0, stream>>>(qkvs, Wbeta + li * 384,
                                                     offs, csrsrc, obuf);
        float* st = bnstat4 + li * 256;
        bn_stats_kernel<<<640, 128, 0, stream>>>(obuf, st, NNODES);
        bn_apply_kernel<<<512, 128, 0, stream>>>(obuf, st, bn_gamma + li * HIDDIM,
                                                 bn_beta + li * HIDDIM, NNODES, Acat);
    }

    // ---- layer 3: t|s GEMM -> fused 8-head aggregate -> mean-V GEMM ->
    //      beta+stats (also zeroes pool out) -> 16-way pool with fused BN ----
    gemm_lds_kernel<unsigned short, 8, 9, KC, 1><<<GSW * 9, 256, 0, stream>>>(
        Acat, Wt3, b3, tbuf, 1152, NNODES);
    attn_big_kernel<<<NNODES, 64, 0, stream>>>(tbuf, Acat, offs, csrsrc, aggb);
    gemm_lds_kernel<float, 32, 1, 1024, 0><<<GSW, 256, 0, stream>>>(
        aggb, Wvm, bvm, omean, HIDDIM, NNODES);
    float* st3 = bnstat4 + 3 * 256;
    beta3_stats_kernel<<<512, 128, 0, stream>>>(omean, tbuf, Wbeta3, hbuf, st3, NNODES, out);
    pool_bn_part_kernel<<<dim3(NGRAPH, 8), 256, 0, stream>>>(
        hbuf, st3, bn_gamma + 3 * HIDDIM, bn_beta + 3 * HIDDIM, gs, ge, out, NNODES);
}